// Round 1
// baseline (2071.644 us; speedup 1.0000x reference)
//
#include <hip/hip_runtime.h>

// Problem constants (match reference file)
#define NN 100000
#define NE 1600000
#define NG 64

// ---------------- degree / norm ----------------
__global__ void degree_kernel(const int* __restrict__ dst, float* __restrict__ deg, int E) {
    int i = blockIdx.x * blockDim.x + threadIdx.x;
    if (i < E) atomicAdd(&deg[dst[i]], 1.0f);
}

__global__ void dinv_kernel(float* deg, int n) {
    int i = blockIdx.x * blockDim.x + threadIdx.x;
    if (i < n) deg[i] = rsqrtf(deg[i] + 1.0f);   // +1 = self loop; always >= 1
}

// ---------------- dense matmul: hout = prelu(hin) @ W ----------------
// slope==nullptr -> identity activation (first layer)
template<int FIN, int FOUT>
__global__ void matmul_kernel(const float* __restrict__ hin, const float* __restrict__ W,
                              const float* __restrict__ slope, float* __restrict__ hout, int n) {
    __shared__ float Wl[FIN * FOUT];
    for (int i = threadIdx.x; i < FIN * FOUT; i += blockDim.x) Wl[i] = W[i];
    __syncthreads();
    int idx = blockIdx.x * blockDim.x + threadIdx.x;
    if (idx >= n * FOUT) return;
    int v = idx / FOUT;
    int f = idx % FOUT;
    float s = slope ? *slope : 1.0f;
    const float* row = hin + (size_t)v * FIN;
    float acc = 0.f;
#pragma unroll
    for (int i = 0; i < FIN; ++i) {
        float x = row[i];
        x = fmaxf(x, 0.f) + s * fminf(x, 0.f);   // prelu (s==1 -> identity)
        acc += x * Wl[i * FOUT + f];
    }
    hout[idx] = acc;
}

// ---------------- init: out = bias + self-loop term ----------------
template<int FOUT>
__global__ void init_kernel(const float* __restrict__ h2, const float* __restrict__ b,
                            const float* __restrict__ dinv, float* __restrict__ out, int n) {
    int idx = blockIdx.x * blockDim.x + threadIdx.x;
    if (idx >= n * FOUT) return;
    int v = idx / FOUT;
    int f = idx & (FOUT - 1);
    float dv = dinv[v];
    out[idx] = b[f] + h2[idx] * dv * dv;
}

// ---------------- edge scatter: out[dst] += h2[src] * dinv[src]*dinv[dst] ----------------
template<int FOUT>
__global__ void edge_kernel(const int* __restrict__ src, const int* __restrict__ dst,
                            const float* __restrict__ dinv, const float* __restrict__ h2,
                            float* __restrict__ out, int E) {
    int idx = blockIdx.x * blockDim.x + threadIdx.x;
    if (idx >= E * FOUT) return;      // E*FOUT <= 204.8M, fits int32
    int e = idx / FOUT;
    int f = idx & (FOUT - 1);
    int s = src[e], d = dst[e];
    float nrm = dinv[s] * dinv[d];
    atomicAdd(&out[(size_t)d * FOUT + f], h2[(size_t)s * FOUT + f] * nrm);
}

// ---------------- pooling: per-graph sums + counts (batch is sorted) ----------------
// block = 128 threads (thread == feature column); each block owns a contiguous node chunk.
// LDS acc[g][f] needs no atomics: column f only ever touched by thread f.
#define POOL_CHUNK 512
__global__ void pool_kernel(const float* __restrict__ h, const int* __restrict__ batch,
                            float* __restrict__ sums, float* __restrict__ cnt, int n) {
    __shared__ float acc[NG * 128];
    __shared__ float cl[NG];
    int tid = threadIdx.x;
    for (int i = tid; i < NG * 128; i += 128) acc[i] = 0.f;
    if (tid < NG) cl[tid] = 0.f;
    __syncthreads();
    int start = blockIdx.x * POOL_CHUNK;
    int end = start + POOL_CHUNK; if (end > n) end = n;
    for (int v = start; v < end; ++v) {
        int g = batch[v];
        acc[g * 128 + tid] += h[(size_t)v * 128 + tid];
        if (tid == 0) cl[g] += 1.f;
    }
    __syncthreads();
    for (int i = tid; i < NG * 128; i += 128)
        if (acc[i] != 0.f) atomicAdd(&sums[i], acc[i]);
    if (tid < NG && cl[tid] != 0.f) atomicAdd(&cnt[tid], cl[tid]);
}

// ---------------- head: out[g][c] = (sums[g]/cnt[g]) @ Wlin + blin ----------------
__global__ void head_kernel(const float* __restrict__ sums, const float* __restrict__ cnt,
                            const float* __restrict__ Wlin, const float* __restrict__ blin,
                            float* __restrict__ out) {
    int t = threadIdx.x;           // 256 = 64 graphs * 4 classes
    int g = t >> 2, c = t & 3;
    float accv = 0.f;
    for (int f = 0; f < 128; ++f) accv += sums[g * 128 + f] * Wlin[f * 4 + c];
    float nrm = fmaxf(cnt[g], 1.f);
    out[g * 4 + c] = accv / nrm + blin[c];
}

extern "C" void kernel_launch(void* const* d_in, const int* in_sizes, int n_in,
                              void* d_out, int out_size, void* d_ws, size_t ws_size,
                              hipStream_t stream) {
    const float* x    = (const float*)d_in[0];
    const int* esrc   = (const int*)d_in[1];
    const int* edst   = (const int*)d_in[2];
    const int* batch  = (const int*)d_in[3];
    const float* W1 = (const float*)d_in[4],  *b1 = (const float*)d_in[5];
    const float* W2 = (const float*)d_in[6],  *b2 = (const float*)d_in[7];
    const float* W3 = (const float*)d_in[8],  *b3 = (const float*)d_in[9];
    const float* W4 = (const float*)d_in[10], *b4 = (const float*)d_in[11];
    const float* a1 = (const float*)d_in[12];
    const float* a2 = (const float*)d_in[13];
    const float* a3 = (const float*)d_in[14];
    const float* Wlin = (const float*)d_in[15], *blin = (const float*)d_in[16];
    float* out = (float*)d_out;

    const int N = NN, E = NE;

    // workspace carve-up
    char* w = (char*)d_ws;
    size_t off = 0;
    auto alloc = [&](size_t bytes) { size_t r = off; off += (bytes + 255) & ~(size_t)255; return r; };
    size_t o_dinv = alloc((size_t)N * 4);
    size_t o_pool = alloc((size_t)NG * 128 * 4);
    size_t o_cnt  = alloc((size_t)NG * 4);
    size_t zero_bytes = off;                 // zero everything up to here
    size_t o_A = alloc((size_t)N * 128 * 4);
    size_t o_B = alloc((size_t)N * 128 * 4);
    (void)ws_size;
    float* dinv = (float*)(w + o_dinv);
    float* pool = (float*)(w + o_pool);
    float* cnt  = (float*)(w + o_cnt);
    float* A = (float*)(w + o_A);
    float* B = (float*)(w + o_B);

    hipMemsetAsync(w, 0, zero_bytes, stream);

    degree_kernel<<<(E + 255) / 256, 256, 0, stream>>>(edst, dinv, E);
    dinv_kernel<<<(N + 255) / 256, 256, 0, stream>>>(dinv, N);

    // layer 1: 8 -> 16  (input x, no activation)
    matmul_kernel<8, 16><<<(N * 16 + 255) / 256, 256, 0, stream>>>(x, W1, nullptr, B, N);
    init_kernel<16><<<(N * 16 + 255) / 256, 256, 0, stream>>>(B, b1, dinv, A, N);
    edge_kernel<16><<<(E * 16 + 255) / 256, 256, 0, stream>>>(esrc, edst, dinv, B, A, E);

    // layer 2: 16 -> 32  (prelu a1 on input)
    matmul_kernel<16, 32><<<(N * 32 + 255) / 256, 256, 0, stream>>>(A, W2, a1, B, N);
    init_kernel<32><<<(N * 32 + 255) / 256, 256, 0, stream>>>(B, b2, dinv, A, N);
    edge_kernel<32><<<(E * 32 + 255) / 256, 256, 0, stream>>>(esrc, edst, dinv, B, A, E);

    // layer 3: 32 -> 64  (prelu a2)
    matmul_kernel<32, 64><<<(N * 64 + 255) / 256, 256, 0, stream>>>(A, W3, a2, B, N);
    init_kernel<64><<<(N * 64 + 255) / 256, 256, 0, stream>>>(B, b3, dinv, A, N);
    edge_kernel<64><<<(E * 64 + 255) / 256, 256, 0, stream>>>(esrc, edst, dinv, B, A, E);

    // layer 4: 64 -> 128 (prelu a3, no output activation)
    matmul_kernel<64, 128><<<(N * 128 + 255) / 256, 256, 0, stream>>>(A, W4, a3, B, N);
    init_kernel<128><<<(N * 128 + 255) / 256, 256, 0, stream>>>(B, b4, dinv, A, N);
    {
        int total = E * 128;                 // 204,800,000
        edge_kernel<128><<<(total + 255) / 256, 256, 0, stream>>>(esrc, edst, dinv, B, A, E);
    }

    // pooling + head
    pool_kernel<<<(N + POOL_CHUNK - 1) / POOL_CHUNK, 128, 0, stream>>>(A, batch, pool, cnt, N);
    head_kernel<<<1, 256, 0, stream>>>(pool, cnt, Wlin, blin, out);
}

// Round 2
// 995.301 us; speedup vs baseline: 2.0814x; 2.0814x over previous
//
#include <hip/hip_runtime.h>

// Problem constants (match reference file)
#define NN 100000
#define NE 1600000
#define NG 64

// ---------------- degree (int) ----------------
__global__ void degree_kernel(const int* __restrict__ dst, int* __restrict__ deg, int E) {
    int i = blockIdx.x * blockDim.x + threadIdx.x;
    if (i < E) atomicAdd(&deg[dst[i]], 1);
}

__global__ void dinv_kernel(const int* __restrict__ deg, float* __restrict__ dinv, int n) {
    int i = blockIdx.x * blockDim.x + threadIdx.x;
    if (i < n) dinv[i] = rsqrtf((float)deg[i] + 1.0f);   // +1 = self loop
}

// ---------------- exclusive scan of deg -> row_off (3 phases) ----------------
__global__ void scan1_kernel(const int* __restrict__ deg, int* __restrict__ excl,
                             int* __restrict__ bsum, int n) {
    __shared__ int buf[2][1024];
    int t = threadIdx.x;
    int gid = blockIdx.x * 1024 + t;
    int v = (gid < n) ? deg[gid] : 0;
    buf[0][t] = v;
    __syncthreads();
    int cur = 0;
    for (int off = 1; off < 1024; off <<= 1) {
        int x = buf[cur][t];
        if (t >= off) x += buf[cur][t - off];
        buf[cur ^ 1][t] = x;
        __syncthreads();
        cur ^= 1;
    }
    int incl = buf[cur][t];
    if (gid < n) excl[gid] = incl - v;          // within-block exclusive
    if (t == 1023) bsum[blockIdx.x] = incl;     // block total
}

__global__ void scan2_kernel(int* __restrict__ bsum, int nb) {   // one block of 128, nb<=128
    __shared__ int buf[2][128];
    int t = threadIdx.x;
    int v = (t < nb) ? bsum[t] : 0;
    buf[0][t] = v;
    __syncthreads();
    int cur = 0;
    for (int off = 1; off < 128; off <<= 1) {
        int x = buf[cur][t];
        if (t >= off) x += buf[cur][t - off];
        buf[cur ^ 1][t] = x;
        __syncthreads();
        cur ^= 1;
    }
    if (t < nb) bsum[t] = buf[cur][t] - v;      // exclusive block offsets
}

__global__ void scan3_kernel(int* __restrict__ excl, const int* __restrict__ bsum,
                             int* __restrict__ cursor, int n) {
    int gid = blockIdx.x * blockDim.x + threadIdx.x;
    if (gid < n) {
        int r = excl[gid] + bsum[gid >> 10];
        excl[gid] = r;        // excl becomes row_off
        cursor[gid] = r;
    }
}

// ---------------- CSR placement ----------------
__global__ void build_csr_kernel(const int* __restrict__ src, const int* __restrict__ dst,
                                 const float* __restrict__ dinv, int* __restrict__ cursor,
                                 int* __restrict__ csr_src, float* __restrict__ csr_w, int E) {
    int e = blockIdx.x * blockDim.x + threadIdx.x;
    if (e < E) {
        int s = src[e], d = dst[e];
        int pos = atomicAdd(&cursor[d], 1);
        csr_src[pos] = s;
        csr_w[pos] = dinv[s] * dinv[d];
    }
}

// ---------------- aggregation: out[v] = dinv[v]^2 * h[v] + sum_in w*h[src] ----------------
// FIN/4 threads per node, float4 per thread. Register accumulate, single store.
template<int FIN>
__global__ void agg_kernel(const float* __restrict__ h, const int* __restrict__ row_off,
                           const int* __restrict__ deg, const float* __restrict__ dinv,
                           const int* __restrict__ csr_src, const float* __restrict__ csr_w,
                           float* __restrict__ out, int n) {
    constexpr int G = FIN / 4;
    int idx = blockIdx.x * blockDim.x + threadIdx.x;
    if (idx >= n * G) return;
    int v = idx / G;
    int c = idx % G;
    const float4* h4 = (const float4*)h;
    float dv = dinv[v];
    float w0 = dv * dv;
    float4 self = h4[(size_t)v * G + c];
    float4 acc = make_float4(self.x * w0, self.y * w0, self.z * w0, self.w * w0);
    int start = row_off[v], cnt = deg[v];
    for (int j = 0; j < cnt; ++j) {
        int s = csr_src[start + j];
        float w = csr_w[start + j];
        float4 hv = h4[(size_t)s * G + c];
        acc.x += hv.x * w; acc.y += hv.y * w; acc.z += hv.z * w; acc.w += hv.w * w;
    }
    ((float4*)out)[(size_t)v * G + c] = acc;
}

// ---------------- fused matmul + bias + prelu: out = prelu(t @ W + b) ----------------
template<int FIN, int FOUT>
__global__ void matmul_kernel(const float* __restrict__ tin, const float* __restrict__ W,
                              const float* __restrict__ b, const float* __restrict__ slope,
                              float* __restrict__ hout, int n) {
    __shared__ float Wl[FIN * FOUT];
    for (int i = threadIdx.x; i < FIN * FOUT; i += blockDim.x) Wl[i] = W[i];
    __syncthreads();
    int idx = blockIdx.x * blockDim.x + threadIdx.x;
    if (idx >= n * FOUT) return;
    int v = idx / FOUT;
    int f = idx % FOUT;
    const float* row = tin + (size_t)v * FIN;
    float acc = b[f];
#pragma unroll
    for (int i = 0; i < FIN; ++i) acc += row[i] * Wl[i * FOUT + f];
    float s = slope ? *slope : 1.0f;
    hout[idx] = fmaxf(acc, 0.f) + s * fminf(acc, 0.f);   // prelu (s==1 -> identity)
}

// ---------------- pooling: per-graph sums + counts (batch is sorted) ----------------
#define POOL_CHUNK 512
__global__ void pool_kernel(const float* __restrict__ h, const int* __restrict__ batch,
                            float* __restrict__ sums, float* __restrict__ cnt, int n) {
    __shared__ float acc[NG * 128];
    __shared__ float cl[NG];
    int tid = threadIdx.x;
    for (int i = tid; i < NG * 128; i += 128) acc[i] = 0.f;
    if (tid < NG) cl[tid] = 0.f;
    __syncthreads();
    int start = blockIdx.x * POOL_CHUNK;
    int end = start + POOL_CHUNK; if (end > n) end = n;
    for (int v = start; v < end; ++v) {
        int g = batch[v];
        acc[g * 128 + tid] += h[(size_t)v * 128 + tid];
        if (tid == 0) cl[g] += 1.f;
    }
    __syncthreads();
    for (int i = tid; i < NG * 128; i += 128)
        if (acc[i] != 0.f) atomicAdd(&sums[i], acc[i]);
    if (tid < NG && cl[tid] != 0.f) atomicAdd(&cnt[tid], cl[tid]);
}

// ---------------- head ----------------
__global__ void head_kernel(const float* __restrict__ sums, const float* __restrict__ cnt,
                            const float* __restrict__ Wlin, const float* __restrict__ blin,
                            float* __restrict__ out) {
    int t = threadIdx.x;           // 256 = 64 graphs * 4 classes
    int g = t >> 2, c = t & 3;
    float accv = 0.f;
    for (int f = 0; f < 128; ++f) accv += sums[g * 128 + f] * Wlin[f * 4 + c];
    float nrm = fmaxf(cnt[g], 1.f);
    out[g * 4 + c] = accv / nrm + blin[c];
}

extern "C" void kernel_launch(void* const* d_in, const int* in_sizes, int n_in,
                              void* d_out, int out_size, void* d_ws, size_t ws_size,
                              hipStream_t stream) {
    const float* x    = (const float*)d_in[0];
    const int* esrc   = (const int*)d_in[1];
    const int* edst   = (const int*)d_in[2];
    const int* batch  = (const int*)d_in[3];
    const float* W1 = (const float*)d_in[4],  *b1 = (const float*)d_in[5];
    const float* W2 = (const float*)d_in[6],  *b2 = (const float*)d_in[7];
    const float* W3 = (const float*)d_in[8],  *b3 = (const float*)d_in[9];
    const float* W4 = (const float*)d_in[10], *b4 = (const float*)d_in[11];
    const float* a1 = (const float*)d_in[12];
    const float* a2 = (const float*)d_in[13];
    const float* a3 = (const float*)d_in[14];
    const float* Wlin = (const float*)d_in[15], *blin = (const float*)d_in[16];
    float* out = (float*)d_out;

    const int N = NN, E = NE;
    const int NB = (N + 1023) / 1024;        // scan1 blocks (98)

    // workspace carve-up
    char* w = (char*)d_ws;
    size_t off = 0;
    auto alloc = [&](size_t bytes) { size_t r = off; off += (bytes + 255) & ~(size_t)255; return r; };
    size_t o_deg  = alloc((size_t)N * 4);          // int, needs zero
    size_t o_pool = alloc((size_t)NG * 128 * 4);   // needs zero
    size_t o_cnt  = alloc((size_t)NG * 4);         // needs zero
    size_t zero_bytes = off;
    size_t o_dinv = alloc((size_t)N * 4);
    size_t o_roff = alloc((size_t)N * 4);
    size_t o_cur  = alloc((size_t)N * 4);
    size_t o_bsum = alloc((size_t)128 * 4);
    size_t o_csrc = alloc((size_t)E * 4);
    size_t o_csw  = alloc((size_t)E * 4);
    size_t o_A    = alloc((size_t)N * 128 * 4);    // activations (max 128)
    size_t o_T    = alloc((size_t)N * 64 * 4);     // agg output (max 64)
    (void)ws_size;
    int*   deg    = (int*)(w + o_deg);
    float* pool   = (float*)(w + o_pool);
    float* cnt    = (float*)(w + o_cnt);
    float* dinv   = (float*)(w + o_dinv);
    int*   roff   = (int*)(w + o_roff);
    int*   cursor = (int*)(w + o_cur);
    int*   bsum   = (int*)(w + o_bsum);
    int*   csrc   = (int*)(w + o_csrc);
    float* csw    = (float*)(w + o_csw);
    float* A      = (float*)(w + o_A);
    float* T      = (float*)(w + o_T);

    hipMemsetAsync(w, 0, zero_bytes, stream);

    // ---- CSR build (once, reused by all 4 layers) ----
    degree_kernel<<<(E + 255) / 256, 256, 0, stream>>>(edst, deg, E);
    dinv_kernel<<<(N + 255) / 256, 256, 0, stream>>>(deg, dinv, N);
    scan1_kernel<<<NB, 1024, 0, stream>>>(deg, roff, bsum, N);
    scan2_kernel<<<1, 128, 0, stream>>>(bsum, NB);
    scan3_kernel<<<(N + 255) / 256, 256, 0, stream>>>(roff, bsum, cursor, N);
    build_csr_kernel<<<(E + 255) / 256, 256, 0, stream>>>(esrc, edst, dinv, cursor, csrc, csw, E);

    // ---- layer 1: agg(x)[8] @ W1 -> 16, prelu a1 ----
    agg_kernel<8><<<(N * 2 + 255) / 256, 256, 0, stream>>>(x, roff, deg, dinv, csrc, csw, T, N);
    matmul_kernel<8, 16><<<(N * 16 + 255) / 256, 256, 0, stream>>>(T, W1, b1, a1, A, N);

    // ---- layer 2: agg(h)[16] @ W2 -> 32, prelu a2 ----
    agg_kernel<16><<<(N * 4 + 255) / 256, 256, 0, stream>>>(A, roff, deg, dinv, csrc, csw, T, N);
    matmul_kernel<16, 32><<<(N * 32 + 255) / 256, 256, 0, stream>>>(T, W2, b2, a2, A, N);

    // ---- layer 3: agg(h)[32] @ W3 -> 64, prelu a3 ----
    agg_kernel<32><<<(N * 8 + 255) / 256, 256, 0, stream>>>(A, roff, deg, dinv, csrc, csw, T, N);
    matmul_kernel<32, 64><<<(N * 64 + 255) / 256, 256, 0, stream>>>(T, W3, b3, a3, A, N);

    // ---- layer 4: agg(h)[64] @ W4 -> 128, no activation ----
    agg_kernel<64><<<(N * 16 + 255) / 256, 256, 0, stream>>>(A, roff, deg, dinv, csrc, csw, T, N);
    matmul_kernel<64, 128><<<(N * 128 + 255) / 256, 256, 0, stream>>>(T, W4, b4, nullptr, A, N);

    // ---- pooling + head ----
    pool_kernel<<<(N + POOL_CHUNK - 1) / POOL_CHUNK, 128, 0, stream>>>(A, batch, pool, cnt, N);
    head_kernel<<<1, 256, 0, stream>>>(pool, cnt, Wlin, blin, out);
}

// Round 3
// 621.076 us; speedup vs baseline: 3.3356x; 1.6025x over previous
//
#include <hip/hip_runtime.h>

// Problem constants (match reference file)
#define NN 100000
#define NE 1600000
#define NG 64

// ---------------- degree (int) ----------------
__global__ void degree_kernel(const int* __restrict__ dst, int* __restrict__ deg, int E) {
    int i = blockIdx.x * blockDim.x + threadIdx.x;
    if (i < E) atomicAdd(&deg[dst[i]], 1);
}

__global__ void dinv_kernel(const int* __restrict__ deg, float* __restrict__ dinv, int n) {
    int i = blockIdx.x * blockDim.x + threadIdx.x;
    if (i < n) dinv[i] = rsqrtf((float)deg[i] + 1.0f);   // +1 = self loop
}

// ---------------- exclusive scan of deg -> row_off (3 phases) ----------------
__global__ void scan1_kernel(const int* __restrict__ deg, int* __restrict__ excl,
                             int* __restrict__ bsum, int n) {
    __shared__ int buf[2][1024];
    int t = threadIdx.x;
    int gid = blockIdx.x * 1024 + t;
    int v = (gid < n) ? deg[gid] : 0;
    buf[0][t] = v;
    __syncthreads();
    int cur = 0;
    for (int off = 1; off < 1024; off <<= 1) {
        int x = buf[cur][t];
        if (t >= off) x += buf[cur][t - off];
        buf[cur ^ 1][t] = x;
        __syncthreads();
        cur ^= 1;
    }
    int incl = buf[cur][t];
    if (gid < n) excl[gid] = incl - v;          // within-block exclusive
    if (t == 1023) bsum[blockIdx.x] = incl;     // block total
}

__global__ void scan2_kernel(int* __restrict__ bsum, int nb) {   // one block of 128, nb<=128
    __shared__ int buf[2][128];
    int t = threadIdx.x;
    int v = (t < nb) ? bsum[t] : 0;
    buf[0][t] = v;
    __syncthreads();
    int cur = 0;
    for (int off = 1; off < 128; off <<= 1) {
        int x = buf[cur][t];
        if (t >= off) x += buf[cur][t - off];
        buf[cur ^ 1][t] = x;
        __syncthreads();
        cur ^= 1;
    }
    if (t < nb) bsum[t] = buf[cur][t] - v;      // exclusive block offsets
}

__global__ void scan3_kernel(int* __restrict__ excl, const int* __restrict__ bsum,
                             int* __restrict__ cursor, int n) {
    int gid = blockIdx.x * blockDim.x + threadIdx.x;
    if (gid < n) {
        int r = excl[gid] + bsum[gid >> 10];
        excl[gid] = r;        // excl becomes row_off
        cursor[gid] = r;
    }
}

// ---------------- CSR placement ----------------
__global__ void build_csr_kernel(const int* __restrict__ src, const int* __restrict__ dst,
                                 const float* __restrict__ dinv, int* __restrict__ cursor,
                                 int* __restrict__ csr_src, float* __restrict__ csr_w, int E) {
    int e = blockIdx.x * blockDim.x + threadIdx.x;
    if (e < E) {
        int s = src[e], d = dst[e];
        int pos = atomicAdd(&cursor[d], 1);
        csr_src[pos] = s;
        csr_w[pos] = dinv[s] * dinv[d];
    }
}

// ---------------- aggregation: out[v] = dinv[v]^2 * h[v] + sum_in w*h[src] ----------------
template<int FIN>
__global__ void agg_kernel(const float* __restrict__ h, const int* __restrict__ row_off,
                           const int* __restrict__ deg, const float* __restrict__ dinv,
                           const int* __restrict__ csr_src, const float* __restrict__ csr_w,
                           float* __restrict__ out, int n) {
    constexpr int G = FIN / 4;
    int idx = blockIdx.x * blockDim.x + threadIdx.x;
    if (idx >= n * G) return;
    int v = idx / G;
    int c = idx % G;
    const float4* h4 = (const float4*)h;
    float dv = dinv[v];
    float w0 = dv * dv;
    float4 self = h4[(size_t)v * G + c];
    float4 acc = make_float4(self.x * w0, self.y * w0, self.z * w0, self.w * w0);
    int start = row_off[v], cnt = deg[v];
    for (int j = 0; j < cnt; ++j) {
        int s = csr_src[start + j];
        float w = csr_w[start + j];
        float4 hv = h4[(size_t)s * G + c];
        acc.x += hv.x * w; acc.y += hv.y * w; acc.z += hv.z * w; acc.w += hv.w * w;
    }
    ((float4*)out)[(size_t)v * G + c] = acc;
}

// ---------------- fused matmul + bias + prelu: out = prelu(t @ W + b) ----------------
// Register micro-tile: each thread computes 4 nodes x 4 outputs (float4).
// Weights staged in LDS as float4 [FIN][FOUT/4]. Row loads are float4.
template<int FIN, int FOUT>
__global__ __launch_bounds__(256) void matmul_kernel(
    const float* __restrict__ tin, const float* __restrict__ W,
    const float* __restrict__ bias, const float* __restrict__ slope,
    float* __restrict__ hout, int n) {
    constexpr int TPN = FOUT / 4;            // threads per node (4 outputs each)
    constexpr int NPB = (256 / TPN) * 4;     // nodes per block
    __shared__ float4 Wl[FIN * TPN];
    const float4* Wg = (const float4*)W;
    for (int i = threadIdx.x; i < FIN * TPN; i += 256) Wl[i] = Wg[i];
    __syncthreads();
    int t = threadIdx.x;
    int grp = t / TPN;
    int f4 = t % TPN;
    int v0 = blockIdx.x * NPB + grp * 4;
    float s = slope ? *slope : 1.0f;
    float4 bv = ((const float4*)bias)[f4];
    float4 acc[4];
#pragma unroll
    for (int nn = 0; nn < 4; ++nn) acc[nn] = bv;
    const float4* tin4 = (const float4*)tin;
#pragma unroll 2
    for (int i = 0; i < FIN; i += 4) {
        float4 r[4];
#pragma unroll
        for (int nn = 0; nn < 4; ++nn) {
            int v = v0 + nn;
            r[nn] = (v < n) ? tin4[(size_t)v * (FIN / 4) + (i >> 2)]
                            : make_float4(0.f, 0.f, 0.f, 0.f);
        }
#pragma unroll
        for (int k = 0; k < 4; ++k) {
            float4 wv = Wl[(i + k) * TPN + f4];
            float rk;
#pragma unroll
            for (int nn = 0; nn < 4; ++nn) {
                rk = (k == 0) ? r[nn].x : (k == 1) ? r[nn].y : (k == 2) ? r[nn].z : r[nn].w;
                acc[nn].x += wv.x * rk;
                acc[nn].y += wv.y * rk;
                acc[nn].z += wv.z * rk;
                acc[nn].w += wv.w * rk;
            }
        }
    }
#pragma unroll
    for (int nn = 0; nn < 4; ++nn) {
        int v = v0 + nn;
        if (v < n) {
            float4 o;
            o.x = fmaxf(acc[nn].x, 0.f) + s * fminf(acc[nn].x, 0.f);
            o.y = fmaxf(acc[nn].y, 0.f) + s * fminf(acc[nn].y, 0.f);
            o.z = fmaxf(acc[nn].z, 0.f) + s * fminf(acc[nn].z, 0.f);
            o.w = fmaxf(acc[nn].w, 0.f) + s * fminf(acc[nn].w, 0.f);
            ((float4*)hout)[(size_t)v * TPN + f4] = o;
        }
    }
}

// ---------------- pooling: batch is sorted -> register accumulate, flush on graph change ----
#define POOL_CHUNK 256
__global__ void pool_kernel(const float* __restrict__ h, const int* __restrict__ batch,
                            float* __restrict__ sums, float* __restrict__ cnt, int n) {
    int tid = threadIdx.x;   // 128 threads = feature columns
    int start = blockIdx.x * POOL_CHUNK;
    if (start >= n) return;
    int end = start + POOL_CHUNK; if (end > n) end = n;
    int curg = batch[start];
    float racc = 0.f, rc = 0.f;
    for (int v = start; v < end; ++v) {
        int g = batch[v];
        if (g != curg) {
            atomicAdd(&sums[curg * 128 + tid], racc);
            if (tid == 0) atomicAdd(&cnt[curg], rc);
            racc = 0.f; rc = 0.f; curg = g;
        }
        racc += h[(size_t)v * 128 + tid];
        rc += 1.f;
    }
    atomicAdd(&sums[curg * 128 + tid], racc);
    if (tid == 0) atomicAdd(&cnt[curg], rc);
}

// ---------------- head ----------------
__global__ void head_kernel(const float* __restrict__ sums, const float* __restrict__ cnt,
                            const float* __restrict__ Wlin, const float* __restrict__ blin,
                            float* __restrict__ out) {
    int t = threadIdx.x;           // 256 = 64 graphs * 4 classes
    int g = t >> 2, c = t & 3;
    float accv = 0.f;
    for (int f = 0; f < 128; ++f) accv += sums[g * 128 + f] * Wlin[f * 4 + c];
    float nrm = fmaxf(cnt[g], 1.f);
    out[g * 4 + c] = accv / nrm + blin[c];
}

extern "C" void kernel_launch(void* const* d_in, const int* in_sizes, int n_in,
                              void* d_out, int out_size, void* d_ws, size_t ws_size,
                              hipStream_t stream) {
    const float* x    = (const float*)d_in[0];
    const int* esrc   = (const int*)d_in[1];
    const int* edst   = (const int*)d_in[2];
    const int* batch  = (const int*)d_in[3];
    const float* W1 = (const float*)d_in[4],  *b1 = (const float*)d_in[5];
    const float* W2 = (const float*)d_in[6],  *b2 = (const float*)d_in[7];
    const float* W3 = (const float*)d_in[8],  *b3 = (const float*)d_in[9];
    const float* W4 = (const float*)d_in[10], *b4 = (const float*)d_in[11];
    const float* a1 = (const float*)d_in[12];
    const float* a2 = (const float*)d_in[13];
    const float* a3 = (const float*)d_in[14];
    const float* Wlin = (const float*)d_in[15], *blin = (const float*)d_in[16];
    float* out = (float*)d_out;

    const int N = NN, E = NE;
    const int NB = (N + 1023) / 1024;        // scan1 blocks (98)

    // workspace carve-up
    char* w = (char*)d_ws;
    size_t off = 0;
    auto alloc = [&](size_t bytes) { size_t r = off; off += (bytes + 255) & ~(size_t)255; return r; };
    size_t o_deg  = alloc((size_t)N * 4);          // int, needs zero
    size_t o_pool = alloc((size_t)NG * 128 * 4);   // needs zero
    size_t o_cnt  = alloc((size_t)NG * 4);         // needs zero
    size_t zero_bytes = off;
    size_t o_dinv = alloc((size_t)N * 4);
    size_t o_roff = alloc((size_t)N * 4);
    size_t o_cur  = alloc((size_t)N * 4);
    size_t o_bsum = alloc((size_t)128 * 4);
    size_t o_csrc = alloc((size_t)E * 4);
    size_t o_csw  = alloc((size_t)E * 4);
    size_t o_A    = alloc((size_t)N * 128 * 4);    // activations (max 128)
    size_t o_T    = alloc((size_t)N * 64 * 4);     // agg output (max 64)
    (void)ws_size;
    int*   deg    = (int*)(w + o_deg);
    float* pool   = (float*)(w + o_pool);
    float* cnt    = (float*)(w + o_cnt);
    float* dinv   = (float*)(w + o_dinv);
    int*   roff   = (int*)(w + o_roff);
    int*   cursor = (int*)(w + o_cur);
    int*   bsum   = (int*)(w + o_bsum);
    int*   csrc   = (int*)(w + o_csrc);
    float* csw    = (float*)(w + o_csw);
    float* A      = (float*)(w + o_A);
    float* T      = (float*)(w + o_T);

    hipMemsetAsync(w, 0, zero_bytes, stream);

    // ---- CSR build (once, reused by all 4 layers) ----
    degree_kernel<<<(E + 255) / 256, 256, 0, stream>>>(edst, deg, E);
    dinv_kernel<<<(N + 255) / 256, 256, 0, stream>>>(deg, dinv, N);
    scan1_kernel<<<NB, 1024, 0, stream>>>(deg, roff, bsum, N);
    scan2_kernel<<<1, 128, 0, stream>>>(bsum, NB);
    scan3_kernel<<<(N + 255) / 256, 256, 0, stream>>>(roff, bsum, cursor, N);
    build_csr_kernel<<<(E + 255) / 256, 256, 0, stream>>>(esrc, edst, dinv, cursor, csrc, csw, E);

    // ---- layer 1: agg(x)[8] @ W1 -> 16, prelu a1 ----
    agg_kernel<8><<<(N * 2 + 255) / 256, 256, 0, stream>>>(x, roff, deg, dinv, csrc, csw, T, N);
    {   constexpr int npb = (256 / (16 / 4)) * 4;   // 256
        matmul_kernel<8, 16><<<(N + npb - 1) / npb, 256, 0, stream>>>(T, W1, b1, a1, A, N); }

    // ---- layer 2: agg(h)[16] @ W2 -> 32, prelu a2 ----
    agg_kernel<16><<<(N * 4 + 255) / 256, 256, 0, stream>>>(A, roff, deg, dinv, csrc, csw, T, N);
    {   constexpr int npb = (256 / (32 / 4)) * 4;   // 128
        matmul_kernel<16, 32><<<(N + npb - 1) / npb, 256, 0, stream>>>(T, W2, b2, a2, A, N); }

    // ---- layer 3: agg(h)[32] @ W3 -> 64, prelu a3 ----
    agg_kernel<32><<<(N * 8 + 255) / 256, 256, 0, stream>>>(A, roff, deg, dinv, csrc, csw, T, N);
    {   constexpr int npb = (256 / (64 / 4)) * 4;   // 64
        matmul_kernel<32, 64><<<(N + npb - 1) / npb, 256, 0, stream>>>(T, W3, b3, a3, A, N); }

    // ---- layer 4: agg(h)[64] @ W4 -> 128, no activation ----
    agg_kernel<64><<<(N * 16 + 255) / 256, 256, 0, stream>>>(A, roff, deg, dinv, csrc, csw, T, N);
    {   constexpr int npb = (256 / (128 / 4)) * 4;  // 32
        matmul_kernel<64, 128><<<(N + npb - 1) / npb, 256, 0, stream>>>(T, W4, b4, nullptr, A, N); }

    // ---- pooling + head ----
    pool_kernel<<<(N + POOL_CHUNK - 1) / POOL_CHUNK, 128, 0, stream>>>(A, batch, pool, cnt, N);
    head_kernel<<<1, 256, 0, stream>>>(pool, cnt, Wlin, blin, out);
}

// Round 4
// 585.210 us; speedup vs baseline: 3.5400x; 1.0613x over previous
//
#include <hip/hip_runtime.h>

// Problem constants (match reference file)
#define NN 100000
#define NE 1600000
#define NG 64

// ---------------- degree (int) ----------------
__global__ void degree_kernel(const int* __restrict__ dst, int* __restrict__ deg, int E) {
    int i = blockIdx.x * blockDim.x + threadIdx.x;
    if (i < E) atomicAdd(&deg[dst[i]], 1);
}

__global__ void dinv_kernel(const int* __restrict__ deg, float* __restrict__ dinv, int n) {
    int i = blockIdx.x * blockDim.x + threadIdx.x;
    if (i < n) dinv[i] = rsqrtf((float)deg[i] + 1.0f);   // +1 = self loop
}

// ---------------- prescale layer-1 input: xs = dinv[v] * x[v]  (FIN=8 -> 2 float4/node) ----
__global__ void prescale_kernel(const float* __restrict__ x, const float* __restrict__ dinv,
                                float* __restrict__ xs, int n) {
    int i = blockIdx.x * blockDim.x + threadIdx.x;   // over n*2 float4s
    if (i >= n * 2) return;
    float dv = dinv[i >> 1];
    float4 v = ((const float4*)x)[i];
    ((float4*)xs)[i] = make_float4(v.x * dv, v.y * dv, v.z * dv, v.w * dv);
}

// ---------------- exclusive scan of deg -> row_off (3 phases) ----------------
__global__ void scan1_kernel(const int* __restrict__ deg, int* __restrict__ excl,
                             int* __restrict__ bsum, int n) {
    __shared__ int buf[2][1024];
    int t = threadIdx.x;
    int gid = blockIdx.x * 1024 + t;
    int v = (gid < n) ? deg[gid] : 0;
    buf[0][t] = v;
    __syncthreads();
    int cur = 0;
    for (int off = 1; off < 1024; off <<= 1) {
        int x = buf[cur][t];
        if (t >= off) x += buf[cur][t - off];
        buf[cur ^ 1][t] = x;
        __syncthreads();
        cur ^= 1;
    }
    int incl = buf[cur][t];
    if (gid < n) excl[gid] = incl - v;          // within-block exclusive
    if (t == 1023) bsum[blockIdx.x] = incl;     // block total
}

__global__ void scan2_kernel(int* __restrict__ bsum, int nb) {   // one block of 128, nb<=128
    __shared__ int buf[2][128];
    int t = threadIdx.x;
    int v = (t < nb) ? bsum[t] : 0;
    buf[0][t] = v;
    __syncthreads();
    int cur = 0;
    for (int off = 1; off < 128; off <<= 1) {
        int x = buf[cur][t];
        if (t >= off) x += buf[cur][t - off];
        buf[cur ^ 1][t] = x;
        __syncthreads();
        cur ^= 1;
    }
    if (t < nb) bsum[t] = buf[cur][t] - v;      // exclusive block offsets
}

__global__ void scan3_kernel(int* __restrict__ excl, const int* __restrict__ bsum,
                             int* __restrict__ cursor, int n) {
    int gid = blockIdx.x * blockDim.x + threadIdx.x;
    if (gid < n) {
        int r = excl[gid] + bsum[gid >> 10];
        excl[gid] = r;        // excl becomes row_off
        cursor[gid] = r;
    }
}

// ---------------- CSR placement (src only; weights folded into activations) ----------------
__global__ void build_csr_kernel(const int* __restrict__ src, const int* __restrict__ dst,
                                 int* __restrict__ cursor, int* __restrict__ csr_src, int E) {
    int e = blockIdx.x * blockDim.x + threadIdx.x;
    if (e < E) {
        int d = dst[e];
        int pos = atomicAdd(&cursor[d], 1);
        csr_src[pos] = src[e];
    }
}

// ---------------- aggregation: out[v] = dinv[v] * (hs[v] + sum_in hs[src]) ----------------
// hs is already pre-scaled by dinv. Pure gather-add, 4x unrolled for MLP.
template<int FIN>
__global__ void agg_kernel(const float* __restrict__ hs, const int* __restrict__ row_off,
                           const int* __restrict__ deg, const float* __restrict__ dinv,
                           const int* __restrict__ csr_src, float* __restrict__ out, int n) {
    constexpr int G = FIN / 4;
    int idx = blockIdx.x * blockDim.x + threadIdx.x;
    if (idx >= n * G) return;
    int v = idx / G;
    int c = idx % G;
    const float4* h4 = (const float4*)hs;
    float4 acc = h4[(size_t)v * G + c];               // self term (already scaled)
    int start = row_off[v], cnt = deg[v];
    const int* __restrict__ row = csr_src + start;
    int j = 0;
    for (; j + 4 <= cnt; j += 4) {
        int s0 = row[j], s1 = row[j + 1], s2 = row[j + 2], s3 = row[j + 3];
        float4 a0 = h4[(size_t)s0 * G + c];
        float4 a1 = h4[(size_t)s1 * G + c];
        float4 a2 = h4[(size_t)s2 * G + c];
        float4 a3 = h4[(size_t)s3 * G + c];
        float4 p0 = make_float4(a0.x + a1.x, a0.y + a1.y, a0.z + a1.z, a0.w + a1.w);
        float4 p1 = make_float4(a2.x + a3.x, a2.y + a3.y, a2.z + a3.z, a2.w + a3.w);
        acc.x += p0.x + p1.x; acc.y += p0.y + p1.y;
        acc.z += p0.z + p1.z; acc.w += p0.w + p1.w;
    }
    for (; j < cnt; ++j) {
        int s = row[j];
        float4 a = h4[(size_t)s * G + c];
        acc.x += a.x; acc.y += a.y; acc.z += a.z; acc.w += a.w;
    }
    float dv = dinv[v];
    ((float4*)out)[(size_t)v * G + c] =
        make_float4(acc.x * dv, acc.y * dv, acc.z * dv, acc.w * dv);
}

// ---------------- fused matmul + bias + prelu (+ optional dinv pre-scale of output) --------
// Each thread computes 4 nodes x 4 outputs. SCALE: store dinv[v]*prelu(...) for next agg.
template<int FIN, int FOUT, bool SCALE>
__global__ __launch_bounds__(256) void matmul_kernel(
    const float* __restrict__ tin, const float* __restrict__ W,
    const float* __restrict__ bias, const float* __restrict__ slope,
    const float* __restrict__ dinv, float* __restrict__ hout, int n) {
    constexpr int TPN = FOUT / 4;            // threads per node (4 outputs each)
    constexpr int NPB = (256 / TPN) * 4;     // nodes per block
    __shared__ float4 Wl[FIN * TPN];
    const float4* Wg = (const float4*)W;
    for (int i = threadIdx.x; i < FIN * TPN; i += 256) Wl[i] = Wg[i];
    __syncthreads();
    int t = threadIdx.x;
    int grp = t / TPN;
    int f4 = t % TPN;
    int v0 = blockIdx.x * NPB + grp * 4;
    float s = slope ? *slope : 1.0f;
    float4 bv = ((const float4*)bias)[f4];
    float4 acc[4];
#pragma unroll
    for (int nn = 0; nn < 4; ++nn) acc[nn] = bv;
    const float4* tin4 = (const float4*)tin;
#pragma unroll 2
    for (int i = 0; i < FIN; i += 4) {
        float4 r[4];
#pragma unroll
        for (int nn = 0; nn < 4; ++nn) {
            int v = v0 + nn;
            r[nn] = (v < n) ? tin4[(size_t)v * (FIN / 4) + (i >> 2)]
                            : make_float4(0.f, 0.f, 0.f, 0.f);
        }
#pragma unroll
        for (int k = 0; k < 4; ++k) {
            float4 wv = Wl[(i + k) * TPN + f4];
            float rk;
#pragma unroll
            for (int nn = 0; nn < 4; ++nn) {
                rk = (k == 0) ? r[nn].x : (k == 1) ? r[nn].y : (k == 2) ? r[nn].z : r[nn].w;
                acc[nn].x += wv.x * rk;
                acc[nn].y += wv.y * rk;
                acc[nn].z += wv.z * rk;
                acc[nn].w += wv.w * rk;
            }
        }
    }
#pragma unroll
    for (int nn = 0; nn < 4; ++nn) {
        int v = v0 + nn;
        if (v < n) {
            float m = SCALE ? dinv[v] : 1.0f;
            float4 o;
            o.x = (fmaxf(acc[nn].x, 0.f) + s * fminf(acc[nn].x, 0.f)) * m;
            o.y = (fmaxf(acc[nn].y, 0.f) + s * fminf(acc[nn].y, 0.f)) * m;
            o.z = (fmaxf(acc[nn].z, 0.f) + s * fminf(acc[nn].z, 0.f)) * m;
            o.w = (fmaxf(acc[nn].w, 0.f) + s * fminf(acc[nn].w, 0.f)) * m;
            ((float4*)hout)[(size_t)v * TPN + f4] = o;
        }
    }
}

// ---------------- pooling: batch is sorted -> register accumulate, flush on graph change ----
#define POOL_CHUNK 256
__global__ void pool_kernel(const float* __restrict__ h, const int* __restrict__ batch,
                            float* __restrict__ sums, float* __restrict__ cnt, int n) {
    int tid = threadIdx.x;   // 128 threads = feature columns
    int start = blockIdx.x * POOL_CHUNK;
    if (start >= n) return;
    int end = start + POOL_CHUNK; if (end > n) end = n;
    int curg = batch[start];
    float racc = 0.f, rc = 0.f;
    for (int v = start; v < end; ++v) {
        int g = batch[v];
        if (g != curg) {
            atomicAdd(&sums[curg * 128 + tid], racc);
            if (tid == 0) atomicAdd(&cnt[curg], rc);
            racc = 0.f; rc = 0.f; curg = g;
        }
        racc += h[(size_t)v * 128 + tid];
        rc += 1.f;
    }
    atomicAdd(&sums[curg * 128 + tid], racc);
    if (tid == 0) atomicAdd(&cnt[curg], rc);
}

// ---------------- head ----------------
__global__ void head_kernel(const float* __restrict__ sums, const float* __restrict__ cnt,
                            const float* __restrict__ Wlin, const float* __restrict__ blin,
                            float* __restrict__ out) {
    int t = threadIdx.x;           // 256 = 64 graphs * 4 classes
    int g = t >> 2, c = t & 3;
    float accv = 0.f;
    for (int f = 0; f < 128; ++f) accv += sums[g * 128 + f] * Wlin[f * 4 + c];
    float nrm = fmaxf(cnt[g], 1.f);
    out[g * 4 + c] = accv / nrm + blin[c];
}

extern "C" void kernel_launch(void* const* d_in, const int* in_sizes, int n_in,
                              void* d_out, int out_size, void* d_ws, size_t ws_size,
                              hipStream_t stream) {
    const float* x    = (const float*)d_in[0];
    const int* esrc   = (const int*)d_in[1];
    const int* edst   = (const int*)d_in[2];
    const int* batch  = (const int*)d_in[3];
    const float* W1 = (const float*)d_in[4],  *b1 = (const float*)d_in[5];
    const float* W2 = (const float*)d_in[6],  *b2 = (const float*)d_in[7];
    const float* W3 = (const float*)d_in[8],  *b3 = (const float*)d_in[9];
    const float* W4 = (const float*)d_in[10], *b4 = (const float*)d_in[11];
    const float* a1 = (const float*)d_in[12];
    const float* a2 = (const float*)d_in[13];
    const float* a3 = (const float*)d_in[14];
    const float* Wlin = (const float*)d_in[15], *blin = (const float*)d_in[16];
    float* out = (float*)d_out;

    const int N = NN, E = NE;
    const int NB = (N + 1023) / 1024;        // scan1 blocks (98)

    // workspace carve-up
    char* w = (char*)d_ws;
    size_t off = 0;
    auto alloc = [&](size_t bytes) { size_t r = off; off += (bytes + 255) & ~(size_t)255; return r; };
    size_t o_deg  = alloc((size_t)N * 4);          // int, needs zero
    size_t o_pool = alloc((size_t)NG * 128 * 4);   // needs zero
    size_t o_cnt  = alloc((size_t)NG * 4);         // needs zero
    size_t zero_bytes = off;
    size_t o_dinv = alloc((size_t)N * 4);
    size_t o_roff = alloc((size_t)N * 4);
    size_t o_cur  = alloc((size_t)N * 4);
    size_t o_bsum = alloc((size_t)128 * 4);
    size_t o_csrc = alloc((size_t)E * 4);
    size_t o_X    = alloc((size_t)N * 8 * 4);      // prescaled x
    size_t o_A    = alloc((size_t)N * 128 * 4);    // activations (max 128)
    size_t o_T    = alloc((size_t)N * 64 * 4);     // agg output (max 64)
    (void)ws_size;
    int*   deg    = (int*)(w + o_deg);
    float* pool   = (float*)(w + o_pool);
    float* cnt    = (float*)(w + o_cnt);
    float* dinv   = (float*)(w + o_dinv);
    int*   roff   = (int*)(w + o_roff);
    int*   cursor = (int*)(w + o_cur);
    int*   bsum   = (int*)(w + o_bsum);
    int*   csrc   = (int*)(w + o_csrc);
    float* XS     = (float*)(w + o_X);
    float* A      = (float*)(w + o_A);
    float* T      = (float*)(w + o_T);

    hipMemsetAsync(w, 0, zero_bytes, stream);

    // ---- CSR build (once, reused by all 4 layers) ----
    degree_kernel<<<(E + 255) / 256, 256, 0, stream>>>(edst, deg, E);
    dinv_kernel<<<(N + 255) / 256, 256, 0, stream>>>(deg, dinv, N);
    scan1_kernel<<<NB, 1024, 0, stream>>>(deg, roff, bsum, N);
    scan2_kernel<<<1, 128, 0, stream>>>(bsum, NB);
    scan3_kernel<<<(N + 255) / 256, 256, 0, stream>>>(roff, bsum, cursor, N);
    build_csr_kernel<<<(E + 255) / 256, 256, 0, stream>>>(esrc, edst, cursor, csrc, E);

    // ---- layer 1: agg(dinv*x)[8] @ W1 -> 16, prelu a1, output pre-scaled ----
    prescale_kernel<<<(N * 2 + 255) / 256, 256, 0, stream>>>(x, dinv, XS, N);
    agg_kernel<8><<<(N * 2 + 255) / 256, 256, 0, stream>>>(XS, roff, deg, dinv, csrc, T, N);
    {   constexpr int npb = (256 / (16 / 4)) * 4;   // 256
        matmul_kernel<8, 16, true><<<(N + npb - 1) / npb, 256, 0, stream>>>(T, W1, b1, a1, dinv, A, N); }

    // ---- layer 2 ----
    agg_kernel<16><<<(N * 4 + 255) / 256, 256, 0, stream>>>(A, roff, deg, dinv, csrc, T, N);
    {   constexpr int npb = (256 / (32 / 4)) * 4;   // 128
        matmul_kernel<16, 32, true><<<(N + npb - 1) / npb, 256, 0, stream>>>(T, W2, b2, a2, dinv, A, N); }

    // ---- layer 3 ----
    agg_kernel<32><<<(N * 8 + 255) / 256, 256, 0, stream>>>(A, roff, deg, dinv, csrc, T, N);
    {   constexpr int npb = (256 / (64 / 4)) * 4;   // 64
        matmul_kernel<32, 64, true><<<(N + npb - 1) / npb, 256, 0, stream>>>(T, W3, b3, a3, dinv, A, N); }

    // ---- layer 4: no activation, output NOT pre-scaled (goes to pooling) ----
    agg_kernel<64><<<(N * 16 + 255) / 256, 256, 0, stream>>>(A, roff, deg, dinv, csrc, T, N);
    {   constexpr int npb = (256 / (128 / 4)) * 4;  // 32
        matmul_kernel<64, 128, false><<<(N + npb - 1) / npb, 256, 0, stream>>>(T, W4, b4, nullptr, dinv, A, N); }

    // ---- pooling + head ----
    pool_kernel<<<(N + POOL_CHUNK - 1) / POOL_CHUNK, 128, 0, stream>>>(A, batch, pool, cnt, N);
    head_kernel<<<1, 256, 0, stream>>>(pool, cnt, Wlin, blin, out);
}

// Round 5
// 528.133 us; speedup vs baseline: 3.9226x; 1.1081x over previous
//
#include <hip/hip_runtime.h>

// Problem constants (match reference file)
#define NN 100000
#define NE 1600000
#define NG 64

// dst-bucketing for the CSR build
#define BSHIFT 7
#define BUCKW (1 << BSHIFT)                 // 128 nodes per bucket
#define NBUCK ((NN + BUCKW - 1) >> BSHIFT)  // 782
#define BIN_CHUNK 8192

// ---------------- degree (int) ----------------
__global__ void degree_kernel(const int* __restrict__ dst, int* __restrict__ deg, int E) {
    int i = blockIdx.x * blockDim.x + threadIdx.x;
    if (i < E) atomicAdd(&deg[dst[i]], 1);
}

__global__ void dinv_kernel(const int* __restrict__ deg, float* __restrict__ dinv, int n) {
    int i = blockIdx.x * blockDim.x + threadIdx.x;
    if (i < n) dinv[i] = rsqrtf((float)deg[i] + 1.0f);   // +1 = self loop
}

// ---------------- prescale layer-1 input: xs = dinv[v] * x[v] ----------------
__global__ void prescale_kernel(const float* __restrict__ x, const float* __restrict__ dinv,
                                float* __restrict__ xs, int n) {
    int i = blockIdx.x * blockDim.x + threadIdx.x;   // over n*2 float4s
    if (i >= n * 2) return;
    float dv = dinv[i >> 1];
    float4 v = ((const float4*)x)[i];
    ((float4*)xs)[i] = make_float4(v.x * dv, v.y * dv, v.z * dv, v.w * dv);
}

// ---------------- exclusive scan (3 phases, reused for nodes and buckets) ----------------
__global__ void scan1_kernel(const int* __restrict__ cntin, int* __restrict__ excl,
                             int* __restrict__ bsum, int n) {
    __shared__ int buf[2][1024];
    int t = threadIdx.x;
    int gid = blockIdx.x * 1024 + t;
    int v = (gid < n) ? cntin[gid] : 0;
    buf[0][t] = v;
    __syncthreads();
    int cur = 0;
    for (int off = 1; off < 1024; off <<= 1) {
        int x = buf[cur][t];
        if (t >= off) x += buf[cur][t - off];
        buf[cur ^ 1][t] = x;
        __syncthreads();
        cur ^= 1;
    }
    int incl = buf[cur][t];
    if (gid < n) excl[gid] = incl - v;          // within-block exclusive
    if (t == 1023) bsum[blockIdx.x] = incl;     // block total
}

__global__ void scan2_kernel(int* __restrict__ bsum, int nb) {   // one block of 128, nb<=128
    __shared__ int buf[2][128];
    int t = threadIdx.x;
    int v = (t < nb) ? bsum[t] : 0;
    buf[0][t] = v;
    __syncthreads();
    int cur = 0;
    for (int off = 1; off < 128; off <<= 1) {
        int x = buf[cur][t];
        if (t >= off) x += buf[cur][t - off];
        buf[cur ^ 1][t] = x;
        __syncthreads();
        cur ^= 1;
    }
    if (t < nb) bsum[t] = buf[cur][t] - v;      // exclusive block offsets
}

// finalize: excl += bsum[block]; optional cursor copy
__global__ void scan3_kernel(int* __restrict__ excl, const int* __restrict__ bsum,
                             int* __restrict__ cursor, int n) {
    int gid = blockIdx.x * blockDim.x + threadIdx.x;
    if (gid < n) {
        int r = excl[gid] + bsum[gid >> 10];
        excl[gid] = r;
        if (cursor) cursor[gid] = r;
    }
}

// ---------------- bucket histogram (LDS-aggregated) ----------------
__global__ __launch_bounds__(256) void bucket_hist_kernel(const int* __restrict__ dst,
                                                          int* __restrict__ bucket_cnt, int E) {
    __shared__ int h[NBUCK];
    for (int i = threadIdx.x; i < NBUCK; i += 256) h[i] = 0;
    __syncthreads();
    int stride = gridDim.x * 256;
    for (int e = blockIdx.x * 256 + threadIdx.x; e < E; e += stride)
        atomicAdd(&h[dst[e] >> BSHIFT], 1);
    __syncthreads();
    for (int i = threadIdx.x; i < NBUCK; i += 256)
        if (h[i]) atomicAdd(&bucket_cnt[i], h[i]);
}

// ---------------- bin edges by dst-bucket (block-private sub-ranges) ----------------
__global__ __launch_bounds__(256) void bin_kernel(const int* __restrict__ src,
                                                  const int* __restrict__ dst,
                                                  int* __restrict__ bcur,
                                                  uint2* __restrict__ binned, int E) {
    __shared__ int h[NBUCK];
    __shared__ int cur[NBUCK];
    for (int i = threadIdx.x; i < NBUCK; i += 256) h[i] = 0;
    __syncthreads();
    int base = blockIdx.x * BIN_CHUNK;
    int end = base + BIN_CHUNK; if (end > E) end = E;
    for (int e = base + threadIdx.x; e < end; e += 256)
        atomicAdd(&h[dst[e] >> BSHIFT], 1);
    __syncthreads();
    for (int i = threadIdx.x; i < NBUCK; i += 256) {
        int c = h[i];
        cur[i] = c ? atomicAdd(&bcur[i], c) : 0;   // reserve contiguous sub-range
    }
    __syncthreads();
    for (int e = base + threadIdx.x; e < end; e += 256) {
        int s = src[e], d = dst[e];
        int pos = atomicAdd(&cur[d >> BSHIFT], 1);
        binned[pos] = make_uint2((unsigned)s, (unsigned)d);
    }
}

// ---------------- final CSR placement: one block per bucket, LDS cursors ----------------
__global__ __launch_bounds__(256) void build2_kernel(const uint2* __restrict__ binned,
                                                     const int* __restrict__ bucket_off,
                                                     const int* __restrict__ bucket_cnt,
                                                     const int* __restrict__ roff,
                                                     int* __restrict__ csr_src, int n) {
    __shared__ int lcur[BUCKW];
    int b = blockIdx.x;
    int v0 = b << BSHIFT;
    for (int i = threadIdx.x; i < BUCKW; i += 256) {
        int v = v0 + i;
        lcur[i] = (v < n) ? roff[v] : 0;
    }
    __syncthreads();
    int start = bucket_off[b], cnt = bucket_cnt[b];
    for (int k = threadIdx.x; k < cnt; k += 256) {
        uint2 e = binned[start + k];
        int pos = atomicAdd(&lcur[e.y & (BUCKW - 1)], 1);
        csr_src[pos] = (int)e.x;
    }
}

// ---------------- aggregation: out[v] = dinv[v] * (hs[v] + sum_in hs[src]) ----------------
template<int FIN>
__global__ void agg_kernel(const float* __restrict__ hs, const int* __restrict__ row_off,
                           const int* __restrict__ deg, const float* __restrict__ dinv,
                           const int* __restrict__ csr_src, float* __restrict__ out, int n) {
    constexpr int G = FIN / 4;
    int idx = blockIdx.x * blockDim.x + threadIdx.x;
    if (idx >= n * G) return;
    int v = idx / G;
    int c = idx % G;
    const float4* h4 = (const float4*)hs;
    float4 acc = h4[(size_t)v * G + c];               // self term (already scaled)
    int start = row_off[v], cnt = deg[v];
    const int* __restrict__ row = csr_src + start;
    int j = 0;
    for (; j + 4 <= cnt; j += 4) {
        int s0 = row[j], s1 = row[j + 1], s2 = row[j + 2], s3 = row[j + 3];
        float4 a0 = h4[(size_t)s0 * G + c];
        float4 a1 = h4[(size_t)s1 * G + c];
        float4 a2 = h4[(size_t)s2 * G + c];
        float4 a3 = h4[(size_t)s3 * G + c];
        float4 p0 = make_float4(a0.x + a1.x, a0.y + a1.y, a0.z + a1.z, a0.w + a1.w);
        float4 p1 = make_float4(a2.x + a3.x, a2.y + a3.y, a2.z + a3.z, a2.w + a3.w);
        acc.x += p0.x + p1.x; acc.y += p0.y + p1.y;
        acc.z += p0.z + p1.z; acc.w += p0.w + p1.w;
    }
    for (; j < cnt; ++j) {
        int s = row[j];
        float4 a = h4[(size_t)s * G + c];
        acc.x += a.x; acc.y += a.y; acc.z += a.z; acc.w += a.w;
    }
    float dv = dinv[v];
    ((float4*)out)[(size_t)v * G + c] =
        make_float4(acc.x * dv, acc.y * dv, acc.z * dv, acc.w * dv);
}

// ---------------- fused matmul + bias + prelu (+ optional dinv pre-scale of output) --------
template<int FIN, int FOUT, bool SCALE>
__global__ __launch_bounds__(256) void matmul_kernel(
    const float* __restrict__ tin, const float* __restrict__ W,
    const float* __restrict__ bias, const float* __restrict__ slope,
    const float* __restrict__ dinv, float* __restrict__ hout, int n) {
    constexpr int TPN = FOUT / 4;            // threads per node (4 outputs each)
    constexpr int NPB = (256 / TPN) * 4;     // nodes per block
    __shared__ float4 Wl[FIN * TPN];
    const float4* Wg = (const float4*)W;
    for (int i = threadIdx.x; i < FIN * TPN; i += 256) Wl[i] = Wg[i];
    __syncthreads();
    int t = threadIdx.x;
    int grp = t / TPN;
    int f4 = t % TPN;
    int v0 = blockIdx.x * NPB + grp * 4;
    float s = slope ? *slope : 1.0f;
    float4 bv = ((const float4*)bias)[f4];
    float4 acc[4];
#pragma unroll
    for (int nn = 0; nn < 4; ++nn) acc[nn] = bv;
    const float4* tin4 = (const float4*)tin;
#pragma unroll 2
    for (int i = 0; i < FIN; i += 4) {
        float4 r[4];
#pragma unroll
        for (int nn = 0; nn < 4; ++nn) {
            int v = v0 + nn;
            r[nn] = (v < n) ? tin4[(size_t)v * (FIN / 4) + (i >> 2)]
                            : make_float4(0.f, 0.f, 0.f, 0.f);
        }
#pragma unroll
        for (int k = 0; k < 4; ++k) {
            float4 wv = Wl[(i + k) * TPN + f4];
            float rk;
#pragma unroll
            for (int nn = 0; nn < 4; ++nn) {
                rk = (k == 0) ? r[nn].x : (k == 1) ? r[nn].y : (k == 2) ? r[nn].z : r[nn].w;
                acc[nn].x += wv.x * rk;
                acc[nn].y += wv.y * rk;
                acc[nn].z += wv.z * rk;
                acc[nn].w += wv.w * rk;
            }
        }
    }
#pragma unroll
    for (int nn = 0; nn < 4; ++nn) {
        int v = v0 + nn;
        if (v < n) {
            float m = SCALE ? dinv[v] : 1.0f;
            float4 o;
            o.x = (fmaxf(acc[nn].x, 0.f) + s * fminf(acc[nn].x, 0.f)) * m;
            o.y = (fmaxf(acc[nn].y, 0.f) + s * fminf(acc[nn].y, 0.f)) * m;
            o.z = (fmaxf(acc[nn].z, 0.f) + s * fminf(acc[nn].z, 0.f)) * m;
            o.w = (fmaxf(acc[nn].w, 0.f) + s * fminf(acc[nn].w, 0.f)) * m;
            ((float4*)hout)[(size_t)v * TPN + f4] = o;
        }
    }
}

// ---------------- pooling: batch is sorted -> register accumulate, flush on graph change ----
#define POOL_CHUNK 256
__global__ void pool_kernel(const float* __restrict__ h, const int* __restrict__ batch,
                            float* __restrict__ sums, float* __restrict__ cnt, int n) {
    int tid = threadIdx.x;   // 128 threads = feature columns
    int start = blockIdx.x * POOL_CHUNK;
    if (start >= n) return;
    int end = start + POOL_CHUNK; if (end > n) end = n;
    int curg = batch[start];
    float racc = 0.f, rc = 0.f;
    for (int v = start; v < end; ++v) {
        int g = batch[v];
        if (g != curg) {
            atomicAdd(&sums[curg * 128 + tid], racc);
            if (tid == 0) atomicAdd(&cnt[curg], rc);
            racc = 0.f; rc = 0.f; curg = g;
        }
        racc += h[(size_t)v * 128 + tid];
        rc += 1.f;
    }
    atomicAdd(&sums[curg * 128 + tid], racc);
    if (tid == 0) atomicAdd(&cnt[curg], rc);
}

// ---------------- head ----------------
__global__ void head_kernel(const float* __restrict__ sums, const float* __restrict__ cnt,
                            const float* __restrict__ Wlin, const float* __restrict__ blin,
                            float* __restrict__ out) {
    int t = threadIdx.x;           // 256 = 64 graphs * 4 classes
    int g = t >> 2, c = t & 3;
    float accv = 0.f;
    for (int f = 0; f < 128; ++f) accv += sums[g * 128 + f] * Wlin[f * 4 + c];
    float nrm = fmaxf(cnt[g], 1.f);
    out[g * 4 + c] = accv / nrm + blin[c];
}

extern "C" void kernel_launch(void* const* d_in, const int* in_sizes, int n_in,
                              void* d_out, int out_size, void* d_ws, size_t ws_size,
                              hipStream_t stream) {
    const float* x    = (const float*)d_in[0];
    const int* esrc   = (const int*)d_in[1];
    const int* edst   = (const int*)d_in[2];
    const int* batch  = (const int*)d_in[3];
    const float* W1 = (const float*)d_in[4],  *b1 = (const float*)d_in[5];
    const float* W2 = (const float*)d_in[6],  *b2 = (const float*)d_in[7];
    const float* W3 = (const float*)d_in[8],  *b3 = (const float*)d_in[9];
    const float* W4 = (const float*)d_in[10], *b4 = (const float*)d_in[11];
    const float* a1 = (const float*)d_in[12];
    const float* a2 = (const float*)d_in[13];
    const float* a3 = (const float*)d_in[14];
    const float* Wlin = (const float*)d_in[15], *blin = (const float*)d_in[16];
    float* out = (float*)d_out;

    const int N = NN, E = NE;
    const int NB = (N + 1023) / 1024;           // node-scan blocks (98)
    const int NBIN = (E + BIN_CHUNK - 1) / BIN_CHUNK;   // 196

    // workspace carve-up
    char* w = (char*)d_ws;
    size_t off = 0;
    auto alloc = [&](size_t bytes) { size_t r = off; off += (bytes + 255) & ~(size_t)255; return r; };
    size_t o_deg  = alloc((size_t)N * 4);          // needs zero
    size_t o_bcnt = alloc((size_t)NBUCK * 4);      // needs zero
    size_t o_pool = alloc((size_t)NG * 128 * 4);   // needs zero
    size_t o_cnt  = alloc((size_t)NG * 4);         // needs zero
    size_t zero_bytes = off;
    size_t o_dinv = alloc((size_t)N * 4);
    size_t o_roff = alloc((size_t)N * 4);
    size_t o_boff = alloc((size_t)NBUCK * 4);
    size_t o_bcur = alloc((size_t)NBUCK * 4);
    size_t o_bsum = alloc((size_t)128 * 4);
    size_t o_csrc = alloc((size_t)E * 4);
    size_t o_bin  = alloc((size_t)E * 8);          // binned (src,dst) pairs
    size_t o_X    = alloc((size_t)N * 8 * 4);      // prescaled x
    size_t o_A    = alloc((size_t)N * 128 * 4);    // activations (max 128)
    size_t o_T    = alloc((size_t)N * 64 * 4);     // agg output (max 64)
    (void)ws_size;
    int*   deg    = (int*)(w + o_deg);
    int*   bcnt   = (int*)(w + o_bcnt);
    float* pool   = (float*)(w + o_pool);
    float* cnt    = (float*)(w + o_cnt);
    float* dinv   = (float*)(w + o_dinv);
    int*   roff   = (int*)(w + o_roff);
    int*   boff   = (int*)(w + o_boff);
    int*   bcur   = (int*)(w + o_bcur);
    int*   bsum   = (int*)(w + o_bsum);
    int*   csrc   = (int*)(w + o_csrc);
    uint2* binned = (uint2*)(w + o_bin);
    float* XS     = (float*)(w + o_X);
    float* A      = (float*)(w + o_A);
    float* T      = (float*)(w + o_T);

    hipMemsetAsync(w, 0, zero_bytes, stream);

    // ---- CSR build via dst-bucket binning (once, reused by all 4 layers) ----
    degree_kernel<<<(E + 255) / 256, 256, 0, stream>>>(edst, deg, E);
    dinv_kernel<<<(N + 255) / 256, 256, 0, stream>>>(deg, dinv, N);
    // node scan: deg -> roff
    scan1_kernel<<<NB, 1024, 0, stream>>>(deg, roff, bsum, N);
    scan2_kernel<<<1, 128, 0, stream>>>(bsum, NB);
    scan3_kernel<<<(N + 255) / 256, 256, 0, stream>>>(roff, bsum, nullptr, N);
    // bucket scan: bcnt -> boff (+ cursor copy)
    bucket_hist_kernel<<<256, 256, 0, stream>>>(edst, bcnt, E);
    scan1_kernel<<<1, 1024, 0, stream>>>(bcnt, boff, bsum, NBUCK);
    scan2_kernel<<<1, 128, 0, stream>>>(bsum, 1);
    scan3_kernel<<<(NBUCK + 255) / 256, 256, 0, stream>>>(boff, bsum, bcur, NBUCK);
    // bin + place
    bin_kernel<<<NBIN, 256, 0, stream>>>(esrc, edst, bcur, binned, E);
    build2_kernel<<<NBUCK, 256, 0, stream>>>(binned, boff, bcnt, roff, csrc, N);

    // ---- layer 1: agg(dinv*x)[8] @ W1 -> 16, prelu a1, output pre-scaled ----
    prescale_kernel<<<(N * 2 + 255) / 256, 256, 0, stream>>>(x, dinv, XS, N);
    agg_kernel<8><<<(N * 2 + 255) / 256, 256, 0, stream>>>(XS, roff, deg, dinv, csrc, T, N);
    {   constexpr int npb = (256 / (16 / 4)) * 4;   // 256
        matmul_kernel<8, 16, true><<<(N + npb - 1) / npb, 256, 0, stream>>>(T, W1, b1, a1, dinv, A, N); }

    // ---- layer 2 ----
    agg_kernel<16><<<(N * 4 + 255) / 256, 256, 0, stream>>>(A, roff, deg, dinv, csrc, T, N);
    {   constexpr int npb = (256 / (32 / 4)) * 4;   // 128
        matmul_kernel<16, 32, true><<<(N + npb - 1) / npb, 256, 0, stream>>>(T, W2, b2, a2, dinv, A, N); }

    // ---- layer 3 ----
    agg_kernel<32><<<(N * 8 + 255) / 256, 256, 0, stream>>>(A, roff, deg, dinv, csrc, T, N);
    {   constexpr int npb = (256 / (64 / 4)) * 4;   // 64
        matmul_kernel<32, 64, true><<<(N + npb - 1) / npb, 256, 0, stream>>>(T, W3, b3, a3, dinv, A, N); }

    // ---- layer 4: no activation, output NOT pre-scaled (goes to pooling) ----
    agg_kernel<64><<<(N * 16 + 255) / 256, 256, 0, stream>>>(A, roff, deg, dinv, csrc, T, N);
    {   constexpr int npb = (256 / (128 / 4)) * 4;  // 32
        matmul_kernel<64, 128, false><<<(N + npb - 1) / npb, 256, 0, stream>>>(T, W4, b4, nullptr, dinv, A, N); }

    // ---- pooling + head ----
    pool_kernel<<<(N + POOL_CHUNK - 1) / POOL_CHUNK, 128, 0, stream>>>(A, batch, pool, cnt, N);
    head_kernel<<<1, 256, 0, stream>>>(pool, cnt, Wlin, blin, out);
}

// Round 6
// 480.246 us; speedup vs baseline: 4.3137x; 1.0997x over previous
//
#include <hip/hip_runtime.h>

// Problem constants (match reference file)
#define NN 100000
#define NE 1600000
#define NG 64

// dst-bucketing for the CSR build
#define BSHIFT 7
#define BUCKW (1 << BSHIFT)                 // 128 nodes per bucket
#define NBUCK ((NN + BUCKW - 1) >> BSHIFT)  // 782
#define BIN_CHUNK 8192

// ---------------- degree + bucket histogram (one edge pass) ----------------
__global__ __launch_bounds__(256) void degree_hist_kernel(const int* __restrict__ dst,
                                                          int* __restrict__ deg,
                                                          int* __restrict__ bucket_cnt, int E) {
    __shared__ int h[NBUCK];
    for (int i = threadIdx.x; i < NBUCK; i += 256) h[i] = 0;
    __syncthreads();
    int stride = gridDim.x * 256;
    for (int e = blockIdx.x * 256 + threadIdx.x; e < E; e += stride) {
        int d = dst[e];
        atomicAdd(&deg[d], 1);
        atomicAdd(&h[d >> BSHIFT], 1);
    }
    __syncthreads();
    for (int i = threadIdx.x; i < NBUCK; i += 256)
        if (h[i]) atomicAdd(&bucket_cnt[i], h[i]);
}

// ---------------- prescale layer-1 input: xs = dinv[v] * x[v] ----------------
__global__ void prescale_kernel(const float* __restrict__ x, const float* __restrict__ dinv,
                                float* __restrict__ xs, int n) {
    int i = blockIdx.x * blockDim.x + threadIdx.x;   // over n*2 float4s
    if (i >= n * 2) return;
    float dv = dinv[i >> 1];
    float4 v = ((const float4*)x)[i];
    ((float4*)xs)[i] = make_float4(v.x * dv, v.y * dv, v.z * dv, v.w * dv);
}

// ---------------- node scan (3 phases) ----------------
__global__ void scan1_kernel(const int* __restrict__ cntin, int* __restrict__ excl,
                             int* __restrict__ bsum, int n) {
    __shared__ int buf[2][1024];
    int t = threadIdx.x;
    int gid = blockIdx.x * 1024 + t;
    int v = (gid < n) ? cntin[gid] : 0;
    buf[0][t] = v;
    __syncthreads();
    int cur = 0;
    for (int off = 1; off < 1024; off <<= 1) {
        int x = buf[cur][t];
        if (t >= off) x += buf[cur][t - off];
        buf[cur ^ 1][t] = x;
        __syncthreads();
        cur ^= 1;
    }
    int incl = buf[cur][t];
    if (gid < n) excl[gid] = incl - v;          // within-block exclusive
    if (t == 1023) bsum[blockIdx.x] = incl;     // block total
}

__global__ void scan2_kernel(int* __restrict__ bsum, int nb) {   // one block of 128, nb<=128
    __shared__ int buf[2][128];
    int t = threadIdx.x;
    int v = (t < nb) ? bsum[t] : 0;
    buf[0][t] = v;
    __syncthreads();
    int cur = 0;
    for (int off = 1; off < 128; off <<= 1) {
        int x = buf[cur][t];
        if (t >= off) x += buf[cur][t - off];
        buf[cur ^ 1][t] = x;
        __syncthreads();
        cur ^= 1;
    }
    if (t < nb) bsum[t] = buf[cur][t] - v;      // exclusive block offsets
}

// finalize node scan + compute dinv in the same pass
__global__ void scan3_node_kernel(int* __restrict__ excl, const int* __restrict__ bsum,
                                  const int* __restrict__ deg, float* __restrict__ dinv, int n) {
    int gid = blockIdx.x * blockDim.x + threadIdx.x;
    if (gid < n) {
        excl[gid] += bsum[gid >> 10];
        dinv[gid] = rsqrtf((float)deg[gid] + 1.0f);   // +1 = self loop
    }
}

// ---------------- bucket scan: single block (NBUCK <= 1024) ----------------
__global__ void bucket_scan_kernel(const int* __restrict__ bcnt, int* __restrict__ boff,
                                   int* __restrict__ bcur) {
    __shared__ int buf[2][1024];
    int t = threadIdx.x;
    int v = (t < NBUCK) ? bcnt[t] : 0;
    buf[0][t] = v;
    __syncthreads();
    int cur = 0;
    for (int off = 1; off < 1024; off <<= 1) {
        int x = buf[cur][t];
        if (t >= off) x += buf[cur][t - off];
        buf[cur ^ 1][t] = x;
        __syncthreads();
        cur ^= 1;
    }
    if (t < NBUCK) {
        int e = buf[cur][t] - v;
        boff[t] = e;
        bcur[t] = e;
    }
}

// ---------------- bin edges by dst-bucket (block-private sub-ranges) ----------------
__global__ __launch_bounds__(256) void bin_kernel(const int* __restrict__ src,
                                                  const int* __restrict__ dst,
                                                  int* __restrict__ bcur,
                                                  uint2* __restrict__ binned, int E) {
    __shared__ int h[NBUCK];
    __shared__ int cur[NBUCK];
    for (int i = threadIdx.x; i < NBUCK; i += 256) h[i] = 0;
    __syncthreads();
    int base = blockIdx.x * BIN_CHUNK;
    int end = base + BIN_CHUNK; if (end > E) end = E;
    for (int e = base + threadIdx.x; e < end; e += 256)
        atomicAdd(&h[dst[e] >> BSHIFT], 1);
    __syncthreads();
    for (int i = threadIdx.x; i < NBUCK; i += 256) {
        int c = h[i];
        cur[i] = c ? atomicAdd(&bcur[i], c) : 0;   // reserve contiguous sub-range
    }
    __syncthreads();
    for (int e = base + threadIdx.x; e < end; e += 256) {
        int s = src[e], d = dst[e];
        int pos = atomicAdd(&cur[d >> BSHIFT], 1);
        binned[pos] = make_uint2((unsigned)s, (unsigned)d);
    }
}

// ---------------- final CSR placement: one block per bucket, LDS cursors ----------------
__global__ __launch_bounds__(256) void build2_kernel(const uint2* __restrict__ binned,
                                                     const int* __restrict__ bucket_off,
                                                     const int* __restrict__ bucket_cnt,
                                                     const int* __restrict__ roff,
                                                     int* __restrict__ csr_src, int n) {
    __shared__ int lcur[BUCKW];
    int b = blockIdx.x;
    int v0 = b << BSHIFT;
    for (int i = threadIdx.x; i < BUCKW; i += 256) {
        int v = v0 + i;
        lcur[i] = (v < n) ? roff[v] : 0;
    }
    __syncthreads();
    int start = bucket_off[b], cnt = bucket_cnt[b];
    for (int k = threadIdx.x; k < cnt; k += 256) {
        uint2 e = binned[start + k];
        int pos = atomicAdd(&lcur[e.y & (BUCKW - 1)], 1);
        csr_src[pos] = (int)e.x;
    }
}

// ---------------- aggregation: out[v] = dinv[v] * (hs[v] + sum_in hs[src]) ----------------
template<int FIN>
__global__ void agg_kernel(const float* __restrict__ hs, const int* __restrict__ row_off,
                           const int* __restrict__ deg, const float* __restrict__ dinv,
                           const int* __restrict__ csr_src, float* __restrict__ out, int n) {
    constexpr int G = FIN / 4;
    int idx = blockIdx.x * blockDim.x + threadIdx.x;
    if (idx >= n * G) return;
    int v = idx / G;
    int c = idx % G;
    const float4* h4 = (const float4*)hs;
    float4 acc = h4[(size_t)v * G + c];               // self term (already scaled)
    int start = row_off[v], cnt = deg[v];
    const int* __restrict__ row = csr_src + start;
    int j = 0;
    for (; j + 4 <= cnt; j += 4) {
        int s0 = row[j], s1 = row[j + 1], s2 = row[j + 2], s3 = row[j + 3];
        float4 a0 = h4[(size_t)s0 * G + c];
        float4 a1 = h4[(size_t)s1 * G + c];
        float4 a2 = h4[(size_t)s2 * G + c];
        float4 a3 = h4[(size_t)s3 * G + c];
        float4 p0 = make_float4(a0.x + a1.x, a0.y + a1.y, a0.z + a1.z, a0.w + a1.w);
        float4 p1 = make_float4(a2.x + a3.x, a2.y + a3.y, a2.z + a3.z, a2.w + a3.w);
        acc.x += p0.x + p1.x; acc.y += p0.y + p1.y;
        acc.z += p0.z + p1.z; acc.w += p0.w + p1.w;
    }
    for (; j < cnt; ++j) {
        int s = row[j];
        float4 a = h4[(size_t)s * G + c];
        acc.x += a.x; acc.y += a.y; acc.z += a.z; acc.w += a.w;
    }
    float dv = dinv[v];
    ((float4*)out)[(size_t)v * G + c] =
        make_float4(acc.x * dv, acc.y * dv, acc.z * dv, acc.w * dv);
}

// ---------------- fused matmul + bias + prelu (+ optional dinv pre-scale of output) --------
template<int FIN, int FOUT, bool SCALE>
__global__ __launch_bounds__(256) void matmul_kernel(
    const float* __restrict__ tin, const float* __restrict__ W,
    const float* __restrict__ bias, const float* __restrict__ slope,
    const float* __restrict__ dinv, float* __restrict__ hout, int n) {
    constexpr int TPN = FOUT / 4;            // threads per node (4 outputs each)
    constexpr int NPB = (256 / TPN) * 4;     // nodes per block
    __shared__ float4 Wl[FIN * TPN];
    const float4* Wg = (const float4*)W;
    for (int i = threadIdx.x; i < FIN * TPN; i += 256) Wl[i] = Wg[i];
    __syncthreads();
    int t = threadIdx.x;
    int grp = t / TPN;
    int f4 = t % TPN;
    int v0 = blockIdx.x * NPB + grp * 4;
    float s = slope ? *slope : 1.0f;
    float4 bv = ((const float4*)bias)[f4];
    float4 acc[4];
#pragma unroll
    for (int nn = 0; nn < 4; ++nn) acc[nn] = bv;
    const float4* tin4 = (const float4*)tin;
#pragma unroll 2
    for (int i = 0; i < FIN; i += 4) {
        float4 r[4];
#pragma unroll
        for (int nn = 0; nn < 4; ++nn) {
            int v = v0 + nn;
            r[nn] = (v < n) ? tin4[(size_t)v * (FIN / 4) + (i >> 2)]
                            : make_float4(0.f, 0.f, 0.f, 0.f);
        }
#pragma unroll
        for (int k = 0; k < 4; ++k) {
            float4 wv = Wl[(i + k) * TPN + f4];
            float rk;
#pragma unroll
            for (int nn = 0; nn < 4; ++nn) {
                rk = (k == 0) ? r[nn].x : (k == 1) ? r[nn].y : (k == 2) ? r[nn].z : r[nn].w;
                acc[nn].x += wv.x * rk;
                acc[nn].y += wv.y * rk;
                acc[nn].z += wv.z * rk;
                acc[nn].w += wv.w * rk;
            }
        }
    }
#pragma unroll
    for (int nn = 0; nn < 4; ++nn) {
        int v = v0 + nn;
        if (v < n) {
            float m = SCALE ? dinv[v] : 1.0f;
            float4 o;
            o.x = (fmaxf(acc[nn].x, 0.f) + s * fminf(acc[nn].x, 0.f)) * m;
            o.y = (fmaxf(acc[nn].y, 0.f) + s * fminf(acc[nn].y, 0.f)) * m;
            o.z = (fmaxf(acc[nn].z, 0.f) + s * fminf(acc[nn].z, 0.f)) * m;
            o.w = (fmaxf(acc[nn].w, 0.f) + s * fminf(acc[nn].w, 0.f)) * m;
            ((float4*)hout)[(size_t)v * TPN + f4] = o;
        }
    }
}

// ---------------- pooling: 8 row-streams x 32 float4-columns per block ----------------
#define POOL_CHUNK 256
__global__ __launch_bounds__(256) void pool_kernel(const float* __restrict__ h,
                                                   const int* __restrict__ batch,
                                                   float* __restrict__ sums,
                                                   float* __restrict__ cnt, int n) {
    int tid = threadIdx.x;
    int c = tid & 31;        // float4 column (128 floats = 32 float4)
    int r = tid >> 5;        // row stream 0..7
    int start = blockIdx.x * POOL_CHUNK;
    if (start >= n) return;
    int end = start + POOL_CHUNK; if (end > n) end = n;
    const float4* h4 = (const float4*)h;
    float4 acc = make_float4(0.f, 0.f, 0.f, 0.f);
    float rc = 0.f;
    int curg = -1;
    for (int v = start + r; v < end; v += 8) {
        int g = batch[v];
        if (g != curg) {
            if (curg >= 0) {
                float* sp = &sums[curg * 128 + c * 4];
                atomicAdd(sp + 0, acc.x); atomicAdd(sp + 1, acc.y);
                atomicAdd(sp + 2, acc.z); atomicAdd(sp + 3, acc.w);
                if (c == 0) atomicAdd(&cnt[curg], rc);
                acc = make_float4(0.f, 0.f, 0.f, 0.f); rc = 0.f;
            }
            curg = g;
        }
        float4 a = h4[(size_t)v * 32 + c];
        acc.x += a.x; acc.y += a.y; acc.z += a.z; acc.w += a.w;
        rc += 1.f;
    }
    if (curg >= 0) {
        float* sp = &sums[curg * 128 + c * 4];
        atomicAdd(sp + 0, acc.x); atomicAdd(sp + 1, acc.y);
        atomicAdd(sp + 2, acc.z); atomicAdd(sp + 3, acc.w);
        if (c == 0) atomicAdd(&cnt[curg], rc);
    }
}

// ---------------- head ----------------
__global__ void head_kernel(const float* __restrict__ sums, const float* __restrict__ cnt,
                            const float* __restrict__ Wlin, const float* __restrict__ blin,
                            float* __restrict__ out) {
    int t = threadIdx.x;           // 256 = 64 graphs * 4 classes
    int g = t >> 2, c = t & 3;
    float accv = 0.f;
    for (int f = 0; f < 128; ++f) accv += sums[g * 128 + f] * Wlin[f * 4 + c];
    float nrm = fmaxf(cnt[g], 1.f);
    out[g * 4 + c] = accv / nrm + blin[c];
}

extern "C" void kernel_launch(void* const* d_in, const int* in_sizes, int n_in,
                              void* d_out, int out_size, void* d_ws, size_t ws_size,
                              hipStream_t stream) {
    const float* x    = (const float*)d_in[0];
    const int* esrc   = (const int*)d_in[1];
    const int* edst   = (const int*)d_in[2];
    const int* batch  = (const int*)d_in[3];
    const float* W1 = (const float*)d_in[4],  *b1 = (const float*)d_in[5];
    const float* W2 = (const float*)d_in[6],  *b2 = (const float*)d_in[7];
    const float* W3 = (const float*)d_in[8],  *b3 = (const float*)d_in[9];
    const float* W4 = (const float*)d_in[10], *b4 = (const float*)d_in[11];
    const float* a1 = (const float*)d_in[12];
    const float* a2 = (const float*)d_in[13];
    const float* a3 = (const float*)d_in[14];
    const float* Wlin = (const float*)d_in[15], *blin = (const float*)d_in[16];
    float* out = (float*)d_out;

    const int N = NN, E = NE;
    const int NB = (N + 1023) / 1024;           // node-scan blocks (98)
    const int NBIN = (E + BIN_CHUNK - 1) / BIN_CHUNK;   // 196

    // workspace carve-up
    char* w = (char*)d_ws;
    size_t off = 0;
    auto alloc = [&](size_t bytes) { size_t r = off; off += (bytes + 255) & ~(size_t)255; return r; };
    size_t o_deg  = alloc((size_t)N * 4);          // needs zero
    size_t o_bcnt = alloc((size_t)NBUCK * 4);      // needs zero
    size_t o_pool = alloc((size_t)NG * 128 * 4);   // needs zero
    size_t o_cnt  = alloc((size_t)NG * 4);         // needs zero
    size_t zero_bytes = off;
    size_t o_dinv = alloc((size_t)N * 4);
    size_t o_roff = alloc((size_t)N * 4);
    size_t o_boff = alloc((size_t)NBUCK * 4);
    size_t o_bcur = alloc((size_t)NBUCK * 4);
    size_t o_bsum = alloc((size_t)128 * 4);
    size_t o_csrc = alloc((size_t)E * 4);
    size_t o_bin  = alloc((size_t)E * 8);          // binned (src,dst) pairs
    size_t o_X    = alloc((size_t)N * 8 * 4);      // prescaled x
    size_t o_A    = alloc((size_t)N * 128 * 4);    // activations (max 128)
    size_t o_T    = alloc((size_t)N * 64 * 4);     // agg output (max 64)
    (void)ws_size;
    int*   deg    = (int*)(w + o_deg);
    int*   bcnt   = (int*)(w + o_bcnt);
    float* pool   = (float*)(w + o_pool);
    float* cnt    = (float*)(w + o_cnt);
    float* dinv   = (float*)(w + o_dinv);
    int*   roff   = (int*)(w + o_roff);
    int*   boff   = (int*)(w + o_boff);
    int*   bcur   = (int*)(w + o_bcur);
    int*   bsum   = (int*)(w + o_bsum);
    int*   csrc   = (int*)(w + o_csrc);
    uint2* binned = (uint2*)(w + o_bin);
    float* XS     = (float*)(w + o_X);
    float* A      = (float*)(w + o_A);
    float* T      = (float*)(w + o_T);

    hipMemsetAsync(w, 0, zero_bytes, stream);

    // ---- CSR build via dst-bucket binning (once, reused by all 4 layers) ----
    degree_hist_kernel<<<256, 256, 0, stream>>>(edst, deg, bcnt, E);
    scan1_kernel<<<NB, 1024, 0, stream>>>(deg, roff, bsum, N);
    scan2_kernel<<<1, 128, 0, stream>>>(bsum, NB);
    scan3_node_kernel<<<(N + 255) / 256, 256, 0, stream>>>(roff, bsum, deg, dinv, N);
    bucket_scan_kernel<<<1, 1024, 0, stream>>>(bcnt, boff, bcur);
    bin_kernel<<<NBIN, 256, 0, stream>>>(esrc, edst, bcur, binned, E);
    build2_kernel<<<NBUCK, 256, 0, stream>>>(binned, boff, bcnt, roff, csrc, N);

    // ---- layer 1: agg(dinv*x)[8] @ W1 -> 16, prelu a1, output pre-scaled ----
    prescale_kernel<<<(N * 2 + 255) / 256, 256, 0, stream>>>(x, dinv, XS, N);
    agg_kernel<8><<<(N * 2 + 255) / 256, 256, 0, stream>>>(XS, roff, deg, dinv, csrc, T, N);
    {   constexpr int npb = (256 / (16 / 4)) * 4;   // 256
        matmul_kernel<8, 16, true><<<(N + npb - 1) / npb, 256, 0, stream>>>(T, W1, b1, a1, dinv, A, N); }

    // ---- layer 2 ----
    agg_kernel<16><<<(N * 4 + 255) / 256, 256, 0, stream>>>(A, roff, deg, dinv, csrc, T, N);
    {   constexpr int npb = (256 / (32 / 4)) * 4;   // 128
        matmul_kernel<16, 32, true><<<(N + npb - 1) / npb, 256, 0, stream>>>(T, W2, b2, a2, dinv, A, N); }

    // ---- layer 3 ----
    agg_kernel<32><<<(N * 8 + 255) / 256, 256, 0, stream>>>(A, roff, deg, dinv, csrc, T, N);
    {   constexpr int npb = (256 / (64 / 4)) * 4;   // 64
        matmul_kernel<32, 64, true><<<(N + npb - 1) / npb, 256, 0, stream>>>(T, W3, b3, a3, dinv, A, N); }

    // ---- layer 4: no activation, output NOT pre-scaled (goes to pooling) ----
    agg_kernel<64><<<(N * 16 + 255) / 256, 256, 0, stream>>>(A, roff, deg, dinv, csrc, T, N);
    {   constexpr int npb = (256 / (128 / 4)) * 4;  // 32
        matmul_kernel<64, 128, false><<<(N + npb - 1) / npb, 256, 0, stream>>>(T, W4, b4, nullptr, dinv, A, N); }

    // ---- pooling + head ----
    pool_kernel<<<(N + POOL_CHUNK - 1) / POOL_CHUNK, 256, 0, stream>>>(A, batch, pool, cnt, N);
    head_kernel<<<1, 256, 0, stream>>>(pool, cnt, Wlin, blin, out);
}

// Round 7
// 419.551 us; speedup vs baseline: 4.9378x; 1.1447x over previous
//
#include <hip/hip_runtime.h>

// Problem constants (match reference file)
#define NN 100000
#define NE 1600000
#define NG 64

// dst-bucketing for the CSR build
#define BSHIFT 7
#define BUCKW (1 << BSHIFT)                 // 128 nodes per bucket
#define NBUCK ((NN + BUCKW - 1) >> BSHIFT)  // 782
#define BIN_CHUNK 8192

// ---------------- bucket histogram (LDS-aggregated, no per-node atomics) ----------------
__global__ __launch_bounds__(256) void bucket_hist_kernel(const int* __restrict__ dst,
                                                          int* __restrict__ bucket_cnt, int E) {
    __shared__ int h[NBUCK];
    for (int i = threadIdx.x; i < NBUCK; i += 256) h[i] = 0;
    __syncthreads();
    int stride = gridDim.x * 256;
    for (int e = blockIdx.x * 256 + threadIdx.x; e < E; e += stride)
        atomicAdd(&h[dst[e] >> BSHIFT], 1);
    __syncthreads();
    for (int i = threadIdx.x; i < NBUCK; i += 256)
        if (h[i]) atomicAdd(&bucket_cnt[i], h[i]);
}

// ---------------- bucket scan: single block (NBUCK <= 1024) ----------------
__global__ void bucket_scan_kernel(const int* __restrict__ bcnt, int* __restrict__ boff,
                                   int* __restrict__ bcur) {
    __shared__ int buf[2][1024];
    int t = threadIdx.x;
    int v = (t < NBUCK) ? bcnt[t] : 0;
    buf[0][t] = v;
    __syncthreads();
    int cur = 0;
    for (int off = 1; off < 1024; off <<= 1) {
        int x = buf[cur][t];
        if (t >= off) x += buf[cur][t - off];
        buf[cur ^ 1][t] = x;
        __syncthreads();
        cur ^= 1;
    }
    if (t < NBUCK) {
        int e = buf[cur][t] - v;
        boff[t] = e;
        bcur[t] = e;
    }
}

// ---------------- bin edges by dst-bucket (block-private sub-ranges) ----------------
__global__ __launch_bounds__(256) void bin_kernel(const int* __restrict__ src,
                                                  const int* __restrict__ dst,
                                                  int* __restrict__ bcur,
                                                  uint2* __restrict__ binned, int E) {
    __shared__ int h[NBUCK];
    __shared__ int cur[NBUCK];
    for (int i = threadIdx.x; i < NBUCK; i += 256) h[i] = 0;
    __syncthreads();
    int base = blockIdx.x * BIN_CHUNK;
    int end = base + BIN_CHUNK; if (end > E) end = E;
    for (int e = base + threadIdx.x; e < end; e += 256)
        atomicAdd(&h[dst[e] >> BSHIFT], 1);
    __syncthreads();
    for (int i = threadIdx.x; i < NBUCK; i += 256) {
        int c = h[i];
        cur[i] = c ? atomicAdd(&bcur[i], c) : 0;   // reserve contiguous sub-range
    }
    __syncthreads();
    for (int e = base + threadIdx.x; e < end; e += 256) {
        int s = src[e], d = dst[e];
        int pos = atomicAdd(&cur[d >> BSHIFT], 1);
        binned[pos] = make_uint2((unsigned)s, (unsigned)d);
    }
}

// ---------------- degree + dinv from binned edges (coalesced, LDS-only atomics) ----------
__global__ __launch_bounds__(256) void deg_dinv_kernel(const uint2* __restrict__ binned,
                                                       const int* __restrict__ bucket_off,
                                                       const int* __restrict__ bucket_cnt,
                                                       int* __restrict__ deg,
                                                       float* __restrict__ dinv, int n) {
    __shared__ int ldeg[BUCKW];
    int b = blockIdx.x;
    for (int i = threadIdx.x; i < BUCKW; i += 256) ldeg[i] = 0;
    __syncthreads();
    int start = bucket_off[b], cnt = bucket_cnt[b];
    for (int k = threadIdx.x; k < cnt; k += 256) {
        unsigned d = binned[start + k].y;
        atomicAdd(&ldeg[d & (BUCKW - 1)], 1);
    }
    __syncthreads();
    int v0 = b << BSHIFT;
    for (int i = threadIdx.x; i < BUCKW; i += 256) {
        int v = v0 + i;
        if (v < n) {
            int dg = ldeg[i];
            deg[v] = dg;
            dinv[v] = rsqrtf((float)dg + 1.0f);   // +1 = self loop
        }
    }
}

// ---------------- node scan (3 phases) ----------------
__global__ void scan1_kernel(const int* __restrict__ cntin, int* __restrict__ excl,
                             int* __restrict__ bsum, int n) {
    __shared__ int buf[2][1024];
    int t = threadIdx.x;
    int gid = blockIdx.x * 1024 + t;
    int v = (gid < n) ? cntin[gid] : 0;
    buf[0][t] = v;
    __syncthreads();
    int cur = 0;
    for (int off = 1; off < 1024; off <<= 1) {
        int x = buf[cur][t];
        if (t >= off) x += buf[cur][t - off];
        buf[cur ^ 1][t] = x;
        __syncthreads();
        cur ^= 1;
    }
    int incl = buf[cur][t];
    if (gid < n) excl[gid] = incl - v;          // within-block exclusive
    if (t == 1023) bsum[blockIdx.x] = incl;     // block total
}

__global__ void scan2_kernel(int* __restrict__ bsum, int nb) {   // one block of 128, nb<=128
    __shared__ int buf[2][128];
    int t = threadIdx.x;
    int v = (t < nb) ? bsum[t] : 0;
    buf[0][t] = v;
    __syncthreads();
    int cur = 0;
    for (int off = 1; off < 128; off <<= 1) {
        int x = buf[cur][t];
        if (t >= off) x += buf[cur][t - off];
        buf[cur ^ 1][t] = x;
        __syncthreads();
        cur ^= 1;
    }
    if (t < nb) bsum[t] = buf[cur][t] - v;      // exclusive block offsets
}

__global__ void scan3_kernel(int* __restrict__ excl, const int* __restrict__ bsum, int n) {
    int gid = blockIdx.x * blockDim.x + threadIdx.x;
    if (gid < n) excl[gid] += bsum[gid >> 10];
}

// ---------------- final CSR placement: one block per bucket, LDS cursors ----------------
__global__ __launch_bounds__(256) void build2_kernel(const uint2* __restrict__ binned,
                                                     const int* __restrict__ bucket_off,
                                                     const int* __restrict__ bucket_cnt,
                                                     const int* __restrict__ roff,
                                                     int* __restrict__ csr_src, int n) {
    __shared__ int lcur[BUCKW];
    int b = blockIdx.x;
    int v0 = b << BSHIFT;
    for (int i = threadIdx.x; i < BUCKW; i += 256) {
        int v = v0 + i;
        lcur[i] = (v < n) ? roff[v] : 0;
    }
    __syncthreads();
    int start = bucket_off[b], cnt = bucket_cnt[b];
    for (int k = threadIdx.x; k < cnt; k += 256) {
        uint2 e = binned[start + k];
        int pos = atomicAdd(&lcur[e.y & (BUCKW - 1)], 1);
        csr_src[pos] = (int)e.x;
    }
}

// ---------------- prescale layer-1 input: xs = dinv[v] * x[v] ----------------
__global__ void prescale_kernel(const float* __restrict__ x, const float* __restrict__ dinv,
                                float* __restrict__ xs, int n) {
    int i = blockIdx.x * blockDim.x + threadIdx.x;   // over n*2 float4s
    if (i >= n * 2) return;
    float dv = dinv[i >> 1];
    float4 v = ((const float4*)x)[i];
    ((float4*)xs)[i] = make_float4(v.x * dv, v.y * dv, v.z * dv, v.w * dv);
}

// ---------------- aggregation: out[v] = dinv[v] * (hs[v] + sum_in hs[src]) ----------------
template<int FIN>
__global__ void agg_kernel(const float* __restrict__ hs, const int* __restrict__ row_off,
                           const int* __restrict__ deg, const float* __restrict__ dinv,
                           const int* __restrict__ csr_src, float* __restrict__ out, int n) {
    constexpr int G = FIN / 4;
    int idx = blockIdx.x * blockDim.x + threadIdx.x;
    if (idx >= n * G) return;
    int v = idx / G;
    int c = idx % G;
    const float4* h4 = (const float4*)hs;
    float4 acc = h4[(size_t)v * G + c];               // self term (already scaled)
    int start = row_off[v], cnt = deg[v];
    const int* __restrict__ row = csr_src + start;
    int j = 0;
    for (; j + 4 <= cnt; j += 4) {
        int s0 = row[j], s1 = row[j + 1], s2 = row[j + 2], s3 = row[j + 3];
        float4 a0 = h4[(size_t)s0 * G + c];
        float4 a1 = h4[(size_t)s1 * G + c];
        float4 a2 = h4[(size_t)s2 * G + c];
        float4 a3 = h4[(size_t)s3 * G + c];
        float4 p0 = make_float4(a0.x + a1.x, a0.y + a1.y, a0.z + a1.z, a0.w + a1.w);
        float4 p1 = make_float4(a2.x + a3.x, a2.y + a3.y, a2.z + a3.z, a2.w + a3.w);
        acc.x += p0.x + p1.x; acc.y += p0.y + p1.y;
        acc.z += p0.z + p1.z; acc.w += p0.w + p1.w;
    }
    for (; j < cnt; ++j) {
        int s = row[j];
        float4 a = h4[(size_t)s * G + c];
        acc.x += a.x; acc.y += a.y; acc.z += a.z; acc.w += a.w;
    }
    float dv = dinv[v];
    ((float4*)out)[(size_t)v * G + c] =
        make_float4(acc.x * dv, acc.y * dv, acc.z * dv, acc.w * dv);
}

// ---------------- fused matmul + bias + prelu (+ optional dinv pre-scale of output) --------
template<int FIN, int FOUT, bool SCALE>
__global__ __launch_bounds__(256) void matmul_kernel(
    const float* __restrict__ tin, const float* __restrict__ W,
    const float* __restrict__ bias, const float* __restrict__ slope,
    const float* __restrict__ dinv, float* __restrict__ hout, int n) {
    constexpr int TPN = FOUT / 4;            // threads per node (4 outputs each)
    constexpr int NPB = (256 / TPN) * 4;     // nodes per block
    __shared__ float4 Wl[FIN * TPN];
    const float4* Wg = (const float4*)W;
    for (int i = threadIdx.x; i < FIN * TPN; i += 256) Wl[i] = Wg[i];
    __syncthreads();
    int t = threadIdx.x;
    int grp = t / TPN;
    int f4 = t % TPN;
    int v0 = blockIdx.x * NPB + grp * 4;
    float s = slope ? *slope : 1.0f;
    float4 bv = ((const float4*)bias)[f4];
    float4 acc[4];
#pragma unroll
    for (int nn = 0; nn < 4; ++nn) acc[nn] = bv;
    const float4* tin4 = (const float4*)tin;
#pragma unroll 2
    for (int i = 0; i < FIN; i += 4) {
        float4 r[4];
#pragma unroll
        for (int nn = 0; nn < 4; ++nn) {
            int v = v0 + nn;
            r[nn] = (v < n) ? tin4[(size_t)v * (FIN / 4) + (i >> 2)]
                            : make_float4(0.f, 0.f, 0.f, 0.f);
        }
#pragma unroll
        for (int k = 0; k < 4; ++k) {
            float4 wv = Wl[(i + k) * TPN + f4];
            float rk;
#pragma unroll
            for (int nn = 0; nn < 4; ++nn) {
                rk = (k == 0) ? r[nn].x : (k == 1) ? r[nn].y : (k == 2) ? r[nn].z : r[nn].w;
                acc[nn].x += wv.x * rk;
                acc[nn].y += wv.y * rk;
                acc[nn].z += wv.z * rk;
                acc[nn].w += wv.w * rk;
            }
        }
    }
#pragma unroll
    for (int nn = 0; nn < 4; ++nn) {
        int v = v0 + nn;
        if (v < n) {
            float m = SCALE ? dinv[v] : 1.0f;
            float4 o;
            o.x = (fmaxf(acc[nn].x, 0.f) + s * fminf(acc[nn].x, 0.f)) * m;
            o.y = (fmaxf(acc[nn].y, 0.f) + s * fminf(acc[nn].y, 0.f)) * m;
            o.z = (fmaxf(acc[nn].z, 0.f) + s * fminf(acc[nn].z, 0.f)) * m;
            o.w = (fmaxf(acc[nn].w, 0.f) + s * fminf(acc[nn].w, 0.f)) * m;
            ((float4*)hout)[(size_t)v * TPN + f4] = o;
        }
    }
}

// ---------------- pooling: 8 row-streams x 32 float4-columns per block ----------------
#define POOL_CHUNK 256
__global__ __launch_bounds__(256) void pool_kernel(const float* __restrict__ h,
                                                   const int* __restrict__ batch,
                                                   float* __restrict__ sums,
                                                   float* __restrict__ cnt, int n) {
    int tid = threadIdx.x;
    int c = tid & 31;        // float4 column (128 floats = 32 float4)
    int r = tid >> 5;        // row stream 0..7
    int start = blockIdx.x * POOL_CHUNK;
    if (start >= n) return;
    int end = start + POOL_CHUNK; if (end > n) end = n;
    const float4* h4 = (const float4*)h;
    float4 acc = make_float4(0.f, 0.f, 0.f, 0.f);
    float rc = 0.f;
    int curg = -1;
    for (int v = start + r; v < end; v += 8) {
        int g = batch[v];
        if (g != curg) {
            if (curg >= 0) {
                float* sp = &sums[curg * 128 + c * 4];
                atomicAdd(sp + 0, acc.x); atomicAdd(sp + 1, acc.y);
                atomicAdd(sp + 2, acc.z); atomicAdd(sp + 3, acc.w);
                if (c == 0) atomicAdd(&cnt[curg], rc);
                acc = make_float4(0.f, 0.f, 0.f, 0.f); rc = 0.f;
            }
            curg = g;
        }
        float4 a = h4[(size_t)v * 32 + c];
        acc.x += a.x; acc.y += a.y; acc.z += a.z; acc.w += a.w;
        rc += 1.f;
    }
    if (curg >= 0) {
        float* sp = &sums[curg * 128 + c * 4];
        atomicAdd(sp + 0, acc.x); atomicAdd(sp + 1, acc.y);
        atomicAdd(sp + 2, acc.z); atomicAdd(sp + 3, acc.w);
        if (c == 0) atomicAdd(&cnt[curg], rc);
    }
}

// ---------------- head ----------------
__global__ void head_kernel(const float* __restrict__ sums, const float* __restrict__ cnt,
                            const float* __restrict__ Wlin, const float* __restrict__ blin,
                            float* __restrict__ out) {
    int t = threadIdx.x;           // 256 = 64 graphs * 4 classes
    int g = t >> 2, c = t & 3;
    float accv = 0.f;
    for (int f = 0; f < 128; ++f) accv += sums[g * 128 + f] * Wlin[f * 4 + c];
    float nrm = fmaxf(cnt[g], 1.f);
    out[g * 4 + c] = accv / nrm + blin[c];
}

extern "C" void kernel_launch(void* const* d_in, const int* in_sizes, int n_in,
                              void* d_out, int out_size, void* d_ws, size_t ws_size,
                              hipStream_t stream) {
    const float* x    = (const float*)d_in[0];
    const int* esrc   = (const int*)d_in[1];
    const int* edst   = (const int*)d_in[2];
    const int* batch  = (const int*)d_in[3];
    const float* W1 = (const float*)d_in[4],  *b1 = (const float*)d_in[5];
    const float* W2 = (const float*)d_in[6],  *b2 = (const float*)d_in[7];
    const float* W3 = (const float*)d_in[8],  *b3 = (const float*)d_in[9];
    const float* W4 = (const float*)d_in[10], *b4 = (const float*)d_in[11];
    const float* a1 = (const float*)d_in[12];
    const float* a2 = (const float*)d_in[13];
    const float* a3 = (const float*)d_in[14];
    const float* Wlin = (const float*)d_in[15], *blin = (const float*)d_in[16];
    float* out = (float*)d_out;

    const int N = NN, E = NE;
    const int NB = (N + 1023) / 1024;           // node-scan blocks (98)
    const int NBIN = (E + BIN_CHUNK - 1) / BIN_CHUNK;   // 196

    // workspace carve-up
    char* w = (char*)d_ws;
    size_t off = 0;
    auto alloc = [&](size_t bytes) { size_t r = off; off += (bytes + 255) & ~(size_t)255; return r; };
    size_t o_bcnt = alloc((size_t)NBUCK * 4);      // needs zero
    size_t o_pool = alloc((size_t)NG * 128 * 4);   // needs zero
    size_t o_cnt  = alloc((size_t)NG * 4);         // needs zero
    size_t zero_bytes = off;
    size_t o_deg  = alloc((size_t)N * 4);
    size_t o_dinv = alloc((size_t)N * 4);
    size_t o_roff = alloc((size_t)N * 4);
    size_t o_boff = alloc((size_t)NBUCK * 4);
    size_t o_bcur = alloc((size_t)NBUCK * 4);
    size_t o_bsum = alloc((size_t)128 * 4);
    size_t o_csrc = alloc((size_t)E * 4);
    size_t o_bin  = alloc((size_t)E * 8);          // binned (src,dst) pairs
    size_t o_X    = alloc((size_t)N * 8 * 4);      // prescaled x
    size_t o_A    = alloc((size_t)N * 128 * 4);    // activations (max 128)
    size_t o_T    = alloc((size_t)N * 64 * 4);     // agg output (max 64)
    (void)ws_size;
    int*   bcnt   = (int*)(w + o_bcnt);
    float* pool   = (float*)(w + o_pool);
    float* cnt    = (float*)(w + o_cnt);
    int*   deg    = (int*)(w + o_deg);
    float* dinv   = (float*)(w + o_dinv);
    int*   roff   = (int*)(w + o_roff);
    int*   boff   = (int*)(w + o_boff);
    int*   bcur   = (int*)(w + o_bcur);
    int*   bsum   = (int*)(w + o_bsum);
    int*   csrc   = (int*)(w + o_csrc);
    uint2* binned = (uint2*)(w + o_bin);
    float* XS     = (float*)(w + o_X);
    float* A      = (float*)(w + o_A);
    float* T      = (float*)(w + o_T);

    hipMemsetAsync(w, 0, zero_bytes, stream);

    // ---- CSR build via dst-bucket binning (once, reused by all 4 layers) ----
    bucket_hist_kernel<<<256, 256, 0, stream>>>(edst, bcnt, E);
    bucket_scan_kernel<<<1, 1024, 0, stream>>>(bcnt, boff, bcur);
    bin_kernel<<<NBIN, 256, 0, stream>>>(esrc, edst, bcur, binned, E);
    deg_dinv_kernel<<<NBUCK, 256, 0, stream>>>(binned, boff, bcnt, deg, dinv, N);
    scan1_kernel<<<NB, 1024, 0, stream>>>(deg, roff, bsum, N);
    scan2_kernel<<<1, 128, 0, stream>>>(bsum, NB);
    scan3_kernel<<<(N + 255) / 256, 256, 0, stream>>>(roff, bsum, N);
    build2_kernel<<<NBUCK, 256, 0, stream>>>(binned, boff, bcnt, roff, csrc, N);

    // ---- layer 1: agg(dinv*x)[8] @ W1 -> 16, prelu a1, output pre-scaled ----
    prescale_kernel<<<(N * 2 + 255) / 256, 256, 0, stream>>>(x, dinv, XS, N);
    agg_kernel<8><<<(N * 2 + 255) / 256, 256, 0, stream>>>(XS, roff, deg, dinv, csrc, T, N);
    {   constexpr int npb = (256 / (16 / 4)) * 4;   // 256
        matmul_kernel<8, 16, true><<<(N + npb - 1) / npb, 256, 0, stream>>>(T, W1, b1, a1, dinv, A, N); }

    // ---- layer 2 ----
    agg_kernel<16><<<(N * 4 + 255) / 256, 256, 0, stream>>>(A, roff, deg, dinv, csrc, T, N);
    {   constexpr int npb = (256 / (32 / 4)) * 4;   // 128
        matmul_kernel<16, 32, true><<<(N + npb - 1) / npb, 256, 0, stream>>>(T, W2, b2, a2, dinv, A, N); }

    // ---- layer 3 ----
    agg_kernel<32><<<(N * 8 + 255) / 256, 256, 0, stream>>>(A, roff, deg, dinv, csrc, T, N);
    {   constexpr int npb = (256 / (64 / 4)) * 4;   // 64
        matmul_kernel<32, 64, true><<<(N + npb - 1) / npb, 256, 0, stream>>>(T, W3, b3, a3, dinv, A, N); }

    // ---- layer 4: no activation, output NOT pre-scaled (goes to pooling) ----
    agg_kernel<64><<<(N * 16 + 255) / 256, 256, 0, stream>>>(A, roff, deg, dinv, csrc, T, N);
    {   constexpr int npb = (256 / (128 / 4)) * 4;  // 32
        matmul_kernel<64, 128, false><<<(N + npb - 1) / npb, 256, 0, stream>>>(T, W4, b4, nullptr, dinv, A, N); }

    // ---- pooling + head ----
    pool_kernel<<<(N + POOL_CHUNK - 1) / POOL_CHUNK, 256, 0, stream>>>(A, batch, pool, cnt, N);
    head_kernel<<<1, 256, 0, stream>>>(pool, cnt, Wlin, blin, out);
}

// Round 8
// 392.566 us; speedup vs baseline: 5.2772x; 1.0687x over previous
//
#include <hip/hip_runtime.h>

// Problem constants (match reference file)
#define NN 100000
#define NE 1600000
#define NG 64

// dst-bucketing for the CSR build
#define BSHIFT 7
#define BUCKW (1 << BSHIFT)                 // 128 nodes per bucket
#define NBUCK ((NN + BUCKW - 1) >> BSHIFT)  // 782
#define BIN_CHUNK 8192

// ---------------- bucket histogram (LDS-aggregated, no per-node atomics) ----------------
__global__ __launch_bounds__(256) void bucket_hist_kernel(const int* __restrict__ dst,
                                                          int* __restrict__ bucket_cnt, int E) {
    __shared__ int h[NBUCK];
    for (int i = threadIdx.x; i < NBUCK; i += 256) h[i] = 0;
    __syncthreads();
    int stride = gridDim.x * 256;
    for (int e = blockIdx.x * 256 + threadIdx.x; e < E; e += stride)
        atomicAdd(&h[dst[e] >> BSHIFT], 1);
    __syncthreads();
    for (int i = threadIdx.x; i < NBUCK; i += 256)
        if (h[i]) atomicAdd(&bucket_cnt[i], h[i]);
}

// ---------------- bucket scan: single block (NBUCK <= 1024) ----------------
__global__ void bucket_scan_kernel(const int* __restrict__ bcnt, int* __restrict__ boff,
                                   int* __restrict__ bcur) {
    __shared__ int buf[2][1024];
    int t = threadIdx.x;
    int v = (t < NBUCK) ? bcnt[t] : 0;
    buf[0][t] = v;
    __syncthreads();
    int cur = 0;
    for (int off = 1; off < 1024; off <<= 1) {
        int x = buf[cur][t];
        if (t >= off) x += buf[cur][t - off];
        buf[cur ^ 1][t] = x;
        __syncthreads();
        cur ^= 1;
    }
    if (t < NBUCK) {
        int e = buf[cur][t] - v;
        boff[t] = e;
        bcur[t] = e;
    }
}

// ---------------- bin edges by dst-bucket (block-private sub-ranges) ----------------
__global__ __launch_bounds__(256) void bin_kernel(const int* __restrict__ src,
                                                  const int* __restrict__ dst,
                                                  int* __restrict__ bcur,
                                                  uint2* __restrict__ binned, int E) {
    __shared__ int h[NBUCK];
    __shared__ int cur[NBUCK];
    for (int i = threadIdx.x; i < NBUCK; i += 256) h[i] = 0;
    __syncthreads();
    int base = blockIdx.x * BIN_CHUNK;
    int end = base + BIN_CHUNK; if (end > E) end = E;
    for (int e = base + threadIdx.x; e < end; e += 256)
        atomicAdd(&h[dst[e] >> BSHIFT], 1);
    __syncthreads();
    for (int i = threadIdx.x; i < NBUCK; i += 256) {
        int c = h[i];
        cur[i] = c ? atomicAdd(&bcur[i], c) : 0;   // reserve contiguous sub-range
    }
    __syncthreads();
    for (int e = base + threadIdx.x; e < end; e += 256) {
        int s = src[e], d = dst[e];
        int pos = atomicAdd(&cur[d >> BSHIFT], 1);
        binned[pos] = make_uint2((unsigned)s, (unsigned)d);
    }
}

// ---------------- degree + dinv from binned edges (coalesced, LDS-only atomics) ----------
__global__ __launch_bounds__(256) void deg_dinv_kernel(const uint2* __restrict__ binned,
                                                       const int* __restrict__ bucket_off,
                                                       const int* __restrict__ bucket_cnt,
                                                       int* __restrict__ deg,
                                                       float* __restrict__ dinv, int n) {
    __shared__ int ldeg[BUCKW];
    int b = blockIdx.x;
    for (int i = threadIdx.x; i < BUCKW; i += 256) ldeg[i] = 0;
    __syncthreads();
    int start = bucket_off[b], cnt = bucket_cnt[b];
    for (int k = threadIdx.x; k < cnt; k += 256) {
        unsigned d = binned[start + k].y;
        atomicAdd(&ldeg[d & (BUCKW - 1)], 1);
    }
    __syncthreads();
    int v0 = b << BSHIFT;
    for (int i = threadIdx.x; i < BUCKW; i += 256) {
        int v = v0 + i;
        if (v < n) {
            int dg = ldeg[i];
            deg[v] = dg;
            dinv[v] = rsqrtf((float)dg + 1.0f);   // +1 = self loop
        }
    }
}

// ---------------- node scan (3 phases) ----------------
__global__ void scan1_kernel(const int* __restrict__ cntin, int* __restrict__ excl,
                             int* __restrict__ bsum, int n) {
    __shared__ int buf[2][1024];
    int t = threadIdx.x;
    int gid = blockIdx.x * 1024 + t;
    int v = (gid < n) ? cntin[gid] : 0;
    buf[0][t] = v;
    __syncthreads();
    int cur = 0;
    for (int off = 1; off < 1024; off <<= 1) {
        int x = buf[cur][t];
        if (t >= off) x += buf[cur][t - off];
        buf[cur ^ 1][t] = x;
        __syncthreads();
        cur ^= 1;
    }
    int incl = buf[cur][t];
    if (gid < n) excl[gid] = incl - v;          // within-block exclusive
    if (t == 1023) bsum[blockIdx.x] = incl;     // block total
}

__global__ void scan2_kernel(int* __restrict__ bsum, int nb) {   // one block of 128, nb<=128
    __shared__ int buf[2][128];
    int t = threadIdx.x;
    int v = (t < nb) ? bsum[t] : 0;
    buf[0][t] = v;
    __syncthreads();
    int cur = 0;
    for (int off = 1; off < 128; off <<= 1) {
        int x = buf[cur][t];
        if (t >= off) x += buf[cur][t - off];
        buf[cur ^ 1][t] = x;
        __syncthreads();
        cur ^= 1;
    }
    if (t < nb) bsum[t] = buf[cur][t] - v;      // exclusive block offsets
}

__global__ void scan3_kernel(int* __restrict__ excl, const int* __restrict__ bsum, int n) {
    int gid = blockIdx.x * blockDim.x + threadIdx.x;
    if (gid < n) excl[gid] += bsum[gid >> 10];
}

// ---------------- final CSR placement: one block per bucket, LDS cursors ----------------
__global__ __launch_bounds__(256) void build2_kernel(const uint2* __restrict__ binned,
                                                     const int* __restrict__ bucket_off,
                                                     const int* __restrict__ bucket_cnt,
                                                     const int* __restrict__ roff,
                                                     int* __restrict__ csr_src, int n) {
    __shared__ int lcur[BUCKW];
    int b = blockIdx.x;
    int v0 = b << BSHIFT;
    for (int i = threadIdx.x; i < BUCKW; i += 256) {
        int v = v0 + i;
        lcur[i] = (v < n) ? roff[v] : 0;
    }
    __syncthreads();
    int start = bucket_off[b], cnt = bucket_cnt[b];
    for (int k = threadIdx.x; k < cnt; k += 256) {
        uint2 e = binned[start + k];
        int pos = atomicAdd(&lcur[e.y & (BUCKW - 1)], 1);
        csr_src[pos] = (int)e.x;
    }
}

// ---------------- prescale layer-1 input: xs = dinv[v] * x[v] ----------------
__global__ void prescale_kernel(const float* __restrict__ x, const float* __restrict__ dinv,
                                float* __restrict__ xs, int n) {
    int i = blockIdx.x * blockDim.x + threadIdx.x;   // over n*2 float4s
    if (i >= n * 2) return;
    float dv = dinv[i >> 1];
    float4 v = ((const float4*)x)[i];
    ((float4*)xs)[i] = make_float4(v.x * dv, v.y * dv, v.z * dv, v.w * dv);
}

// ---------------- aggregation: out[v] = dinv[v] * (hs[v] + sum_in hs[src]) ----------------
template<int FIN>
__global__ void agg_kernel(const float* __restrict__ hs, const int* __restrict__ row_off,
                           const int* __restrict__ deg, const float* __restrict__ dinv,
                           const int* __restrict__ csr_src, float* __restrict__ out, int n) {
    constexpr int G = FIN / 4;
    int idx = blockIdx.x * blockDim.x + threadIdx.x;
    if (idx >= n * G) return;
    int v = idx / G;
    int c = idx % G;
    const float4* h4 = (const float4*)hs;
    float4 acc = h4[(size_t)v * G + c];               // self term (already scaled)
    int start = row_off[v], cnt = deg[v];
    const int* __restrict__ row = csr_src + start;
    int j = 0;
    for (; j + 4 <= cnt; j += 4) {
        int s0 = row[j], s1 = row[j + 1], s2 = row[j + 2], s3 = row[j + 3];
        float4 a0 = h4[(size_t)s0 * G + c];
        float4 a1 = h4[(size_t)s1 * G + c];
        float4 a2 = h4[(size_t)s2 * G + c];
        float4 a3 = h4[(size_t)s3 * G + c];
        float4 p0 = make_float4(a0.x + a1.x, a0.y + a1.y, a0.z + a1.z, a0.w + a1.w);
        float4 p1 = make_float4(a2.x + a3.x, a2.y + a3.y, a2.z + a3.z, a2.w + a3.w);
        acc.x += p0.x + p1.x; acc.y += p0.y + p1.y;
        acc.z += p0.z + p1.z; acc.w += p0.w + p1.w;
    }
    for (; j < cnt; ++j) {
        int s = row[j];
        float4 a = h4[(size_t)s * G + c];
        acc.x += a.x; acc.y += a.y; acc.z += a.z; acc.w += a.w;
    }
    float dv = dinv[v];
    ((float4*)out)[(size_t)v * G + c] =
        make_float4(acc.x * dv, acc.y * dv, acc.z * dv, acc.w * dv);
}

// ---------------- fused matmul + bias + prelu (+ optional dinv pre-scale of output) --------
template<int FIN, int FOUT, bool SCALE>
__global__ __launch_bounds__(256) void matmul_kernel(
    const float* __restrict__ tin, const float* __restrict__ W,
    const float* __restrict__ bias, const float* __restrict__ slope,
    const float* __restrict__ dinv, float* __restrict__ hout, int n) {
    constexpr int TPN = FOUT / 4;            // threads per node (4 outputs each)
    constexpr int NPB = (256 / TPN) * 4;     // nodes per block
    __shared__ float4 Wl[FIN * TPN];
    const float4* Wg = (const float4*)W;
    for (int i = threadIdx.x; i < FIN * TPN; i += 256) Wl[i] = Wg[i];
    __syncthreads();
    int t = threadIdx.x;
    int grp = t / TPN;
    int f4 = t % TPN;
    int v0 = blockIdx.x * NPB + grp * 4;
    float s = slope ? *slope : 1.0f;
    float4 bv = ((const float4*)bias)[f4];
    float4 acc[4];
#pragma unroll
    for (int nn = 0; nn < 4; ++nn) acc[nn] = bv;
    const float4* tin4 = (const float4*)tin;
#pragma unroll 2
    for (int i = 0; i < FIN; i += 4) {
        float4 r[4];
#pragma unroll
        for (int nn = 0; nn < 4; ++nn) {
            int v = v0 + nn;
            r[nn] = (v < n) ? tin4[(size_t)v * (FIN / 4) + (i >> 2)]
                            : make_float4(0.f, 0.f, 0.f, 0.f);
        }
#pragma unroll
        for (int k = 0; k < 4; ++k) {
            float4 wv = Wl[(i + k) * TPN + f4];
            float rk;
#pragma unroll
            for (int nn = 0; nn < 4; ++nn) {
                rk = (k == 0) ? r[nn].x : (k == 1) ? r[nn].y : (k == 2) ? r[nn].z : r[nn].w;
                acc[nn].x += wv.x * rk;
                acc[nn].y += wv.y * rk;
                acc[nn].z += wv.z * rk;
                acc[nn].w += wv.w * rk;
            }
        }
    }
#pragma unroll
    for (int nn = 0; nn < 4; ++nn) {
        int v = v0 + nn;
        if (v < n) {
            float m = SCALE ? dinv[v] : 1.0f;
            float4 o;
            o.x = (fmaxf(acc[nn].x, 0.f) + s * fminf(acc[nn].x, 0.f)) * m;
            o.y = (fmaxf(acc[nn].y, 0.f) + s * fminf(acc[nn].y, 0.f)) * m;
            o.z = (fmaxf(acc[nn].z, 0.f) + s * fminf(acc[nn].z, 0.f)) * m;
            o.w = (fmaxf(acc[nn].w, 0.f) + s * fminf(acc[nn].w, 0.f)) * m;
            ((float4*)hout)[(size_t)v * TPN + f4] = o;
        }
    }
}

// ---------------- fused layer-4 aggregation + pooling ----------------
// T[v] = dinv[v]*(hs[v] + sum_in hs[src]) is never materialized; per-graph sums
// P[g] = sum_{v in g} T[v] accumulate in registers (batch is sorted), flushed on change.
// 256 threads = 16 row-streams x 16 float4-columns (64 features).
#define APCHUNK 256
__global__ __launch_bounds__(256) void agg_pool_kernel(
    const float* __restrict__ hs, const int* __restrict__ row_off,
    const int* __restrict__ deg, const float* __restrict__ dinv,
    const int* __restrict__ csr_src, const int* __restrict__ batch,
    float* __restrict__ sums, float* __restrict__ cnt, int n) {
    int tid = threadIdx.x;
    int c = tid & 15;        // float4 column (64 floats = 16 float4)
    int r = tid >> 4;        // row stream 0..15
    int start = blockIdx.x * APCHUNK;
    if (start >= n) return;
    int end = start + APCHUNK; if (end > n) end = n;
    const float4* h4 = (const float4*)hs;
    float4 pacc = make_float4(0.f, 0.f, 0.f, 0.f);
    float rc = 0.f;
    int curg = -1;
    for (int v = start + r; v < end; v += 16) {
        int g = batch[v];
        if (g != curg) {
            if (curg >= 0) {
                float* sp = &sums[curg * 64 + c * 4];
                atomicAdd(sp + 0, pacc.x); atomicAdd(sp + 1, pacc.y);
                atomicAdd(sp + 2, pacc.z); atomicAdd(sp + 3, pacc.w);
                if (c == 0) atomicAdd(&cnt[curg], rc);
                pacc = make_float4(0.f, 0.f, 0.f, 0.f); rc = 0.f;
            }
            curg = g;
        }
        // compute T[v] column c on the fly
        float4 acc = h4[(size_t)v * 16 + c];
        int s0 = row_off[v], dcnt = deg[v];
        const int* __restrict__ row = csr_src + s0;
        int j = 0;
        for (; j + 4 <= dcnt; j += 4) {
            int i0 = row[j], i1 = row[j + 1], i2 = row[j + 2], i3 = row[j + 3];
            float4 a0 = h4[(size_t)i0 * 16 + c];
            float4 a1 = h4[(size_t)i1 * 16 + c];
            float4 a2 = h4[(size_t)i2 * 16 + c];
            float4 a3 = h4[(size_t)i3 * 16 + c];
            acc.x += (a0.x + a1.x) + (a2.x + a3.x);
            acc.y += (a0.y + a1.y) + (a2.y + a3.y);
            acc.z += (a0.z + a1.z) + (a2.z + a3.z);
            acc.w += (a0.w + a1.w) + (a2.w + a3.w);
        }
        for (; j < dcnt; ++j) {
            int s = row[j];
            float4 a = h4[(size_t)s * 16 + c];
            acc.x += a.x; acc.y += a.y; acc.z += a.z; acc.w += a.w;
        }
        float dv = dinv[v];
        pacc.x += acc.x * dv; pacc.y += acc.y * dv;
        pacc.z += acc.z * dv; pacc.w += acc.w * dv;
        rc += 1.f;
    }
    if (curg >= 0) {
        float* sp = &sums[curg * 64 + c * 4];
        atomicAdd(sp + 0, pacc.x); atomicAdd(sp + 1, pacc.y);
        atomicAdd(sp + 2, pacc.z); atomicAdd(sp + 3, pacc.w);
        if (c == 0) atomicAdd(&cnt[curg], rc);
    }
}

// ---------------- head: out[g] = (P[g] @ (W4@Wlin)) / cnt[g] + (b4@Wlin + blin) ----------
__global__ __launch_bounds__(256) void head_kernel(
    const float* __restrict__ P, const float* __restrict__ cnt,
    const float* __restrict__ W4, const float* __restrict__ b4,
    const float* __restrict__ Wlin, const float* __restrict__ blin,
    float* __restrict__ out) {
    __shared__ float M[64 * 4];   // W4 @ Wlin
    __shared__ float bb[4];       // b4 @ Wlin + blin
    int t = threadIdx.x;          // 256 = 64 * 4
    {
        int k = t >> 2, cc = t & 3;
        float m = 0.f;
        for (int j = 0; j < 128; ++j) m += W4[k * 128 + j] * Wlin[j * 4 + cc];
        M[k * 4 + cc] = m;
    }
    if (t < 4) {
        float v = blin[t];
        for (int j = 0; j < 128; ++j) v += b4[j] * Wlin[j * 4 + t];
        bb[t] = v;
    }
    __syncthreads();
    int g = t >> 2, cc = t & 3;
    float a = 0.f;
    for (int k = 0; k < 64; ++k) a += P[g * 64 + k] * M[k * 4 + cc];
    out[g * 4 + cc] = a / fmaxf(cnt[g], 1.f) + bb[cc];
}

extern "C" void kernel_launch(void* const* d_in, const int* in_sizes, int n_in,
                              void* d_out, int out_size, void* d_ws, size_t ws_size,
                              hipStream_t stream) {
    const float* x    = (const float*)d_in[0];
    const int* esrc   = (const int*)d_in[1];
    const int* edst   = (const int*)d_in[2];
    const int* batch  = (const int*)d_in[3];
    const float* W1 = (const float*)d_in[4],  *b1 = (const float*)d_in[5];
    const float* W2 = (const float*)d_in[6],  *b2 = (const float*)d_in[7];
    const float* W3 = (const float*)d_in[8],  *b3 = (const float*)d_in[9];
    const float* W4 = (const float*)d_in[10], *b4 = (const float*)d_in[11];
    const float* a1 = (const float*)d_in[12];
    const float* a2 = (const float*)d_in[13];
    const float* a3 = (const float*)d_in[14];
    const float* Wlin = (const float*)d_in[15], *blin = (const float*)d_in[16];
    float* out = (float*)d_out;

    const int N = NN, E = NE;
    const int NB = (N + 1023) / 1024;           // node-scan blocks (98)
    const int NBIN = (E + BIN_CHUNK - 1) / BIN_CHUNK;   // 196

    // workspace carve-up
    char* w = (char*)d_ws;
    size_t off = 0;
    auto alloc = [&](size_t bytes) { size_t r = off; off += (bytes + 255) & ~(size_t)255; return r; };
    size_t o_bcnt = alloc((size_t)NBUCK * 4);      // needs zero
    size_t o_pool = alloc((size_t)NG * 64 * 4);    // needs zero (pooled T sums)
    size_t o_cnt  = alloc((size_t)NG * 4);         // needs zero
    size_t zero_bytes = off;
    size_t o_deg  = alloc((size_t)N * 4);
    size_t o_dinv = alloc((size_t)N * 4);
    size_t o_roff = alloc((size_t)N * 4);
    size_t o_boff = alloc((size_t)NBUCK * 4);
    size_t o_bcur = alloc((size_t)NBUCK * 4);
    size_t o_bsum = alloc((size_t)128 * 4);
    size_t o_csrc = alloc((size_t)E * 4);
    size_t o_bin  = alloc((size_t)E * 8);          // binned (src,dst) pairs
    size_t o_X    = alloc((size_t)N * 8 * 4);      // prescaled x
    size_t o_A    = alloc((size_t)N * 64 * 4);     // activations (max 64 now)
    size_t o_T    = alloc((size_t)N * 32 * 4);     // agg output (max 32 now)
    (void)ws_size;
    int*   bcnt   = (int*)(w + o_bcnt);
    float* pool   = (float*)(w + o_pool);
    float* cnt    = (float*)(w + o_cnt);
    int*   deg    = (int*)(w + o_deg);
    float* dinv   = (float*)(w + o_dinv);
    int*   roff   = (int*)(w + o_roff);
    int*   boff   = (int*)(w + o_boff);
    int*   bcur   = (int*)(w + o_bcur);
    int*   bsum   = (int*)(w + o_bsum);
    int*   csrc   = (int*)(w + o_csrc);
    uint2* binned = (uint2*)(w + o_bin);
    float* XS     = (float*)(w + o_X);
    float* A      = (float*)(w + o_A);
    float* T      = (float*)(w + o_T);

    hipMemsetAsync(w, 0, zero_bytes, stream);

    // ---- CSR build via dst-bucket binning (once, reused by all 4 layers) ----
    bucket_hist_kernel<<<256, 256, 0, stream>>>(edst, bcnt, E);
    bucket_scan_kernel<<<1, 1024, 0, stream>>>(bcnt, boff, bcur);
    bin_kernel<<<NBIN, 256, 0, stream>>>(esrc, edst, bcur, binned, E);
    deg_dinv_kernel<<<NBUCK, 256, 0, stream>>>(binned, boff, bcnt, deg, dinv, N);
    scan1_kernel<<<NB, 1024, 0, stream>>>(deg, roff, bsum, N);
    scan2_kernel<<<1, 128, 0, stream>>>(bsum, NB);
    scan3_kernel<<<(N + 255) / 256, 256, 0, stream>>>(roff, bsum, N);
    build2_kernel<<<NBUCK, 256, 0, stream>>>(binned, boff, bcnt, roff, csrc, N);

    // ---- layer 1: agg(dinv*x)[8] @ W1 -> 16, prelu a1, output pre-scaled ----
    prescale_kernel<<<(N * 2 + 255) / 256, 256, 0, stream>>>(x, dinv, XS, N);
    agg_kernel<8><<<(N * 2 + 255) / 256, 256, 0, stream>>>(XS, roff, deg, dinv, csrc, T, N);
    {   constexpr int npb = (256 / (16 / 4)) * 4;   // 256
        matmul_kernel<8, 16, true><<<(N + npb - 1) / npb, 256, 0, stream>>>(T, W1, b1, a1, dinv, A, N); }

    // ---- layer 2 ----
    agg_kernel<16><<<(N * 4 + 255) / 256, 256, 0, stream>>>(A, roff, deg, dinv, csrc, T, N);
    {   constexpr int npb = (256 / (32 / 4)) * 4;   // 128
        matmul_kernel<16, 32, true><<<(N + npb - 1) / npb, 256, 0, stream>>>(T, W2, b2, a2, dinv, A, N); }

    // ---- layer 3 ----
    agg_kernel<32><<<(N * 8 + 255) / 256, 256, 0, stream>>>(A, roff, deg, dinv, csrc, T, N);
    {   constexpr int npb = (256 / (64 / 4)) * 4;   // 64
        matmul_kernel<32, 64, true><<<(N + npb - 1) / npb, 256, 0, stream>>>(T, W3, b3, a3, dinv, A, N); }

    // ---- layer 4: fused agg + pool (T never materialized; matmul folded into head) ----
    agg_pool_kernel<<<(N + APCHUNK - 1) / APCHUNK, 256, 0, stream>>>(
        A, roff, deg, dinv, csrc, batch, pool, cnt, N);
    head_kernel<<<1, 256, 0, stream>>>(pool, cnt, W4, b4, Wlin, blin, out);
}